// Round 13
// baseline (575.883 us; speedup 1.0000x reference)
//
#include <hip/hip_runtime.h>

#define TPB 256
typedef unsigned int uint;
typedef unsigned short ushort;
typedef long long ll;
typedef __attribute__((ext_vector_type(8))) short bf16x8;
typedef __attribute__((ext_vector_type(8))) ushort u16x8;
typedef __attribute__((ext_vector_type(4))) float f32x4;

__device__ __forceinline__ float bf2f(ushort h) {
  return __uint_as_float(((uint)h) << 16);
}
__device__ __forceinline__ ushort f2bf(float f) {
  uint u = __float_as_uint(f);
  u += 0x7fffu + ((u >> 16) & 1u);
  return (ushort)(u >> 16);
}

// ---------------- one-dispatch prep payload ----------------
struct PJobs {
  const float* a[10];
  const float* bavg[10];
  ushort* out[10];
  const float* ba[2];
  const float* bb[2];
  float* bo[2];
};

// ------- mega1: convert (BW, non-temporal) || rank (atomic-latency) || prep ---------
// NT loads/stores on the convert branch keep the 2.4MB cnt arrays L2-resident
// so rank's atomics stay L2-speed instead of HBM RMW.
__global__ __launch_bounds__(TPB) void mega1_k(
    const float* __restrict__ xm, ushort* __restrict__ xmh, ll n8, int gConv,
    const int* __restrict__ src_cm, const int* __restrict__ dst_cm,
    const int* __restrict__ src_am, const int* __restrict__ dst_am, int E, int g2E,
    int* __restrict__ cnt_m_cm, int* __restrict__ cnt_m_am,
    int* __restrict__ cnt_c, int* __restrict__ cnt_a,
    int* __restrict__ rk_m_cm, int* __restrict__ rk_c,
    int* __restrict__ rk_m_am, int* __restrict__ rk_a,
    PJobs J) {
  int b = blockIdx.x;
  int t = threadIdx.x;
  if (b < gConv) {  // xm f32 -> bf16 (non-temporal: bypass L2)
    ll i = (ll)b * TPB + t;
    if (i >= n8) return;
    const f32x4* p = (const f32x4*)(xm + i * 8);
    f32x4 a = __builtin_nontemporal_load(p);
    f32x4 bb = __builtin_nontemporal_load(p + 1);
    u16x8 v;
    v[0] = f2bf(a[0]); v[1] = f2bf(a[1]); v[2] = f2bf(a[2]); v[3] = f2bf(a[3]);
    v[4] = f2bf(bb[0]); v[5] = f2bf(bb[1]); v[6] = f2bf(bb[2]); v[7] = f2bf(bb[3]);
    __builtin_nontemporal_store(v, (u16x8*)&xmh[i * 8]);
    return;
  }
  b -= gConv;
  if (b < g2E) {  // counts + per-edge local rank (one atomic pass)
    int i = b * TPB + t;
    if (i < E) {
      rk_m_cm[i] = atomicAdd(&cnt_m_cm[dst_cm[i]], 1);
      rk_c[i]    = atomicAdd(&cnt_c[src_cm[i]], 1);
    } else if (i < 2 * E) {
      int e = i - E;
      rk_m_am[e] = atomicAdd(&cnt_m_am[dst_am[e]], 1);
      rk_a[e]    = atomicAdd(&cnt_a[src_am[e]], 1);
    }
    return;
  }
  b -= g2E;  // prep: 10 weight transposes + 2 bias averages (513 blocks)
  if (b == 512) {
    if (t < 128) J.bo[0][t] = 0.5f * (J.ba[0][t] + J.bb[0][t]);
    else if (t < 256) J.bo[1][t - 128] = 0.5f * (J.ba[1][t - 128] + J.bb[1][t - 128]);
    return;
  }
  int job, idx, K;
  if (b < 384) { job = b >> 6; idx = ((b & 63) << 8) | t; K = 128; }
  else { int bb2 = b - 384; job = 6 + (bb2 >> 5); idx = ((bb2 & 31) << 8) | t; K = 64; }
  int col = idx / K, k = idx - col * K;
  float v = J.a[job][k * 128 + col];
  if (J.bavg[job]) v = 0.5f * (v + J.bavg[job][k * 128 + col]);
  J.out[job][idx] = f2bf(v);
}

// ---------------- CSR build helpers ----------------
__device__ __forceinline__ void rel_map(int b, int nb0, int nb1, int nb2, int nb3,
                                        int& r, int& lb) {
  if (b < nb0) { r = 0; lb = b; }
  else if (b < nb0 + nb1) { r = 1; lb = b - nb0; }
  else if (b < nb0 + nb1 + nb2) { r = 2; lb = b - nb0 - nb1; }
  else { r = 3; lb = b - nb0 - nb1 - nb2; }
}

__global__ __launch_bounds__(TPB) void bsum_rinv_k(
    const int* __restrict__ c0, int n0, const int* __restrict__ c1, int n1,
    const int* __restrict__ c2, int n2, const int* __restrict__ c3, int n3,
    int* __restrict__ bsum, float* __restrict__ rinv, int nm2, int total, int nbtot) {
  __shared__ int lds[TPB];
  int b = blockIdx.x;
  int t = threadIdx.x;
  if (b >= nbtot) {  // rinv branch (cnt block is contiguous starting at c0)
    int i = (b - nbtot) * TPB + t;
    if (i < total) {
      float scale = (i < nm2) ? 0.5f : 1.0f;
      rinv[i] = scale / fmaxf((float)c0[i], 1.0f);
    }
    return;
  }
  int nb0 = (n0 + TPB - 1) / TPB, nb1 = (n1 + TPB - 1) / TPB;
  int nb2 = (n2 + TPB - 1) / TPB, nb3 = (n3 + TPB - 1) / TPB;
  int r, lb;
  rel_map(b, nb0, nb1, nb2, nb3, r, lb);
  const int* cnt = (r == 0) ? c0 : (r == 1) ? c1 : (r == 2) ? c2 : c3;
  int n = (r == 0) ? n0 : (r == 1) ? n1 : (r == 2) ? n2 : n3;
  int i = lb * TPB + t;
  lds[t] = (i < n) ? cnt[i] : 0;
  __syncthreads();
  for (int off = 128; off > 0; off >>= 1) {
    if (t < off) lds[t] += lds[t + off];
    __syncthreads();
  }
  if (t == 0) bsum[r * 1024 + lb] = lds[0];
}

__global__ __launch_bounds__(TPB) void scan_all_k(int* __restrict__ bsum,
                                                  int n0, int n1, int n2, int n3) {
  __shared__ int lds[TPB];
  int r = blockIdx.x;
  int n = (r == 0) ? n0 : (r == 1) ? n1 : (r == 2) ? n2 : n3;
  int nb = (n + TPB - 1) / TPB;
  int* bs = bsum + r * 1024;
  int t = threadIdx.x;
  int offset = 0;
  for (int base = 0; base < nb; base += TPB) {
    int v = (base + t < nb) ? bs[base + t] : 0;
    lds[t] = v;
    __syncthreads();
    for (int off = 1; off < TPB; off <<= 1) {
      int add = (t >= off) ? lds[t - off] : 0;
      __syncthreads();
      lds[t] += add;
      __syncthreads();
    }
    int incl = lds[t];
    if (base + t < nb) bs[base + t] = offset + incl - v;
    int tot = lds[TPB - 1];
    __syncthreads();
    offset += tot;
  }
}

__global__ __launch_bounds__(TPB) void finalize_all_k(
    const int* __restrict__ c0, int n0, int* __restrict__ rp0,
    const int* __restrict__ c1, int n1, int* __restrict__ rp1,
    const int* __restrict__ c2, int n2, int* __restrict__ rp2,
    const int* __restrict__ c3, int n3, int* __restrict__ rp3,
    const int* __restrict__ bsum) {
  __shared__ int lds[TPB];
  int nb0 = (n0 + TPB - 1) / TPB, nb1 = (n1 + TPB - 1) / TPB;
  int nb2 = (n2 + TPB - 1) / TPB, nb3 = (n3 + TPB - 1) / TPB;
  int r, lb;
  rel_map(blockIdx.x, nb0, nb1, nb2, nb3, r, lb);
  const int* cnt = (r == 0) ? c0 : (r == 1) ? c1 : (r == 2) ? c2 : c3;
  int* rowptr = (r == 0) ? rp0 : (r == 1) ? rp1 : (r == 2) ? rp2 : rp3;
  int n = (r == 0) ? n0 : (r == 1) ? n1 : (r == 2) ? n2 : n3;
  int t = threadIdx.x;
  int i = lb * TPB + t;
  int v = (i < n) ? cnt[i] : 0;
  lds[t] = v;
  __syncthreads();
  for (int off = 1; off < TPB; off <<= 1) {
    int add = (t >= off) ? lds[t - off] : 0;
    __syncthreads();
    lds[t] += add;
    __syncthreads();
  }
  int ex = lds[t] - v + bsum[r * 1024 + lb];
  if (i < n) {
    rowptr[i] = ex;
    if (i == n - 1) rowptr[n] = ex + v;
  }
}

// -------- merged crew+cast gather, 16 lanes/row, 2-way unrolled degree loop ---------
__global__ __launch_bounds__(TPB) void gatherw2_k(
    const ushort* __restrict__ xmh,
    const int* __restrict__ rp1, const int* __restrict__ pm1,
    const float* __restrict__ ri1, int N1, ushort* __restrict__ o1,
    const int* __restrict__ rp2, const int* __restrict__ pm2,
    const float* __restrict__ ri2, int N2, ushort* __restrict__ o2, int g1) {
  int b = blockIdx.x;
  const int* rowptr; const int* perm; const float* rinv; int N; ushort* out;
  int lb;
  if (b < g1) { rowptr = rp1; perm = pm1; rinv = ri1; N = N1; out = o1; lb = b; }
  else { rowptr = rp2; perm = pm2; rinv = ri2; N = N2; out = o2; lb = b - g1; }
  int nid = lb * 16 + (threadIdx.x >> 4);
  if (nid >= N) return;
  int d = (threadIdx.x & 15) << 3;
  int j = rowptr[nid], e = rowptr[nid + 1];
  float aA[8] = {0.f}, aB[8] = {0.f};
  for (; j + 1 < e; j += 2) {
    u16x8 v0 = *(const u16x8*)&xmh[((ll)perm[j] << 7) + d];
    u16x8 v1 = *(const u16x8*)&xmh[((ll)perm[j + 1] << 7) + d];
#pragma unroll
    for (int k = 0; k < 8; ++k) { aA[k] += bf2f(v0[k]); aB[k] += bf2f(v1[k]); }
  }
  if (j < e) {
    u16x8 v0 = *(const u16x8*)&xmh[((ll)perm[j] << 7) + d];
#pragma unroll
    for (int k = 0; k < 8; ++k) aA[k] += bf2f(v0[k]);
  }
  float r = rinv[nid];
  u16x8 o;
#pragma unroll
  for (int k = 0; k < 8; ++k) o[k] = f2bf((aA[k] + aB[k]) * r);
  *(u16x8*)&out[((ll)nid << 7) + d] = o;
}

// -------- dual-CSR gather into bf16 A (single RMW), 2-way unrolled ------------------
__global__ __launch_bounds__(TPB) void gather2_k(
    const ushort* __restrict__ s1, const ushort* __restrict__ s2,
    const int* __restrict__ rp1, const int* __restrict__ pm1, const float* __restrict__ ri1,
    const int* __restrict__ rp2, const int* __restrict__ pm2, const float* __restrict__ ri2,
    int N, ushort* __restrict__ out) {
  int nid = blockIdx.x * 16 + (threadIdx.x >> 4);
  if (nid >= N) return;
  int d = (threadIdx.x & 15) << 3;
  float aA[8] = {0.f}, aB[8] = {0.f};
  {
    int j = rp1[nid], e = rp1[nid + 1];
    for (; j + 1 < e; j += 2) {
      u16x8 v0 = *(const u16x8*)&s1[((ll)pm1[j] << 7) + d];
      u16x8 v1 = *(const u16x8*)&s1[((ll)pm1[j + 1] << 7) + d];
#pragma unroll
      for (int k = 0; k < 8; ++k) { aA[k] += bf2f(v0[k]); aB[k] += bf2f(v1[k]); }
    }
    if (j < e) {
      u16x8 v0 = *(const u16x8*)&s1[((ll)pm1[j] << 7) + d];
#pragma unroll
      for (int k = 0; k < 8; ++k) aA[k] += bf2f(v0[k]);
    }
  }
  float r1 = ri1[nid];
  float res[8];
#pragma unroll
  for (int k = 0; k < 8; ++k) res[k] = (aA[k] + aB[k]) * r1;
  float bA[8] = {0.f}, bB[8] = {0.f};
  {
    int j = rp2[nid], e = rp2[nid + 1];
    for (; j + 1 < e; j += 2) {
      u16x8 v0 = *(const u16x8*)&s2[((ll)pm2[j] << 7) + d];
      u16x8 v1 = *(const u16x8*)&s2[((ll)pm2[j + 1] << 7) + d];
#pragma unroll
      for (int k = 0; k < 8; ++k) { bA[k] += bf2f(v0[k]); bB[k] += bf2f(v1[k]); }
    }
    if (j < e) {
      u16x8 v0 = *(const u16x8*)&s2[((ll)pm2[j] << 7) + d];
#pragma unroll
      for (int k = 0; k < 8; ++k) bA[k] += bf2f(v0[k]);
    }
  }
  float r2 = ri2[nid];
  ushort* p = &out[((ll)nid << 7) + d];
  u16x8 cur = *(u16x8*)p;
  u16x8 o;
#pragma unroll
  for (int k = 0; k < 8; ++k)
    o[k] = f2bf(bf2f(cur[k]) + res[k] + (bA[k] + bB[k]) * r2);
  *(u16x8*)p = o;
}

// ---------------- final linear: relu(X bf16) (M x 128) @ (128 x 16) + b -------------
__global__ __launch_bounds__(TPB) void final_k(const ushort* __restrict__ X,
                                               const float* __restrict__ W,
                                               const float* __restrict__ b,
                                               float* __restrict__ out, int M) {
  __shared__ float lw[128 * 16];
  __shared__ float lb[16];
  int t = threadIdx.x;
  for (int i = t; i < 2048; i += TPB) lw[i] = W[i];
  if (t < 16) lb[t] = b[t];
  __syncthreads();
  ll row = (ll)blockIdx.x * TPB + t;
  if (row >= M) return;
  float acc[16];
#pragma unroll
  for (int c = 0; c < 16; ++c) acc[c] = lb[c];
  const ushort* xr = &X[row * 128];
  for (int k = 0; k < 128; k += 8) {
    u16x8 xv = *(const u16x8*)&xr[k];
#pragma unroll
    for (int j = 0; j < 8; ++j) {
      float xs = fmaxf(bf2f(xv[j]), 0.f);
#pragma unroll
      for (int c = 0; c < 16; ++c) acc[c] = fmaf(xs, lw[(k + j) * 16 + c], acc[c]);
    }
  }
#pragma unroll
  for (int c = 0; c < 16; c += 4) {
    float4 o; o.x = acc[c]; o.y = acc[c + 1]; o.z = acc[c + 2]; o.w = acc[c + 3];
    *(float4*)&out[row * 16 + c] = o;
  }
}

// ------- mega2: optional atomic-free fill section || up to 5 MFMA GEMM problems -----
#define BK 64
#define XPITCH 72
#define CPITCH 132
struct CArgs {
  const void* X0; const ushort* WT0; int K0; int xb0;
  const void* X1; const ushort* WT1; int K1; int xb1;
  int nseg; const float* bias; void* out; int M; int nblk;
};
struct FArgs {
  const int* src_cm; const int* dst_cm; const int* src_am; const int* dst_am; int E;
  const int* rp_m_cm; const int* rp_m_am; const int* rp_c; const int* rp_a;
  const int* rk_m_cm; const int* rk_c; const int* rk_m_am; const int* rk_a;
  int* pm_m_cm; int* pm_m_am; int* pm_c; int* pm_a;
};

template <bool XRELU>
__global__ __launch_bounds__(TPB) void mega2_k(FArgs F, int gFill,
                                               CArgs a0, CArgs a1, CArgs a2,
                                               CArgs a3, CArgs a4) {
  __shared__ ushort sbuf[2 * 128 * XPITCH];  // Xs/Ws in K-loop; C-tile in epilogue
  int bx = blockIdx.x;
  if (bx < gFill) {  // fill via precomputed ranks: NO atomics
    int i = bx * TPB + threadIdx.x;
    if (i < F.E) {
      int s = F.src_cm[i], d = F.dst_cm[i];
      F.pm_m_cm[F.rp_m_cm[d] + F.rk_m_cm[i]] = s;
      F.pm_c[F.rp_c[s] + F.rk_c[i]] = d;
    } else if (i < 2 * F.E) {
      int e = i - F.E;
      int s = F.src_am[e], d = F.dst_am[e];
      F.pm_m_am[F.rp_m_am[d] + F.rk_m_am[e]] = s;
      F.pm_a[F.rp_a[s] + F.rk_a[e]] = d;
    }
    return;
  }
  bx -= gFill;
  const int o0 = a0.nblk, o1 = o0 + a1.nblk, o2 = o1 + a2.nblk, o3 = o2 + a3.nblk;
  const CArgs& a = (bx < o0) ? a0 : (bx < o1) ? a1 : (bx < o2) ? a2
                   : (bx < o3) ? a3 : a4;
  const int blk = bx - ((bx < o0) ? 0 : (bx < o1) ? o0 : (bx < o2) ? o1
                        : (bx < o3) ? o2 : o3);

  ushort* Xs = sbuf;
  ushort* Ws = sbuf + 128 * XPITCH;
  const int t = threadIdx.x;
  const int lane = t & 63;
  const int wid = t >> 6;
  const int wm = (wid >> 1) << 6;
  const int wn = (wid & 1) << 6;
  const ll rbase = (ll)blk * 128;
  const int M = a.M;

  f32x4 acc[4][4];
#pragma unroll
  for (int mi = 0; mi < 4; ++mi)
#pragma unroll
    for (int ni = 0; ni < 4; ++ni) acc[mi][ni] = (f32x4){0.f, 0.f, 0.f, 0.f};

  for (int s = 0; s < a.nseg; ++s) {
    const void* Xv = s ? a.X1 : a.X0;
    const ushort* WT = s ? a.WT1 : a.WT0;
    const int K = s ? a.K1 : a.K0;
    const int xb = s ? a.xb1 : a.xb0;
    for (int k0 = 0; k0 < K; k0 += BK) {
      __syncthreads();
#pragma unroll
      for (int i = 0; i < 4; ++i) {
        int idx8 = t + i * TPB;
        int row = idx8 >> 3;
        int kb = (idx8 & 7) << 3;
        u16x8 xv;
        ll grow = rbase + row;
        if (grow < M) {
          if (xb) {
            xv = *(const u16x8*)((const ushort*)Xv + grow * K + k0 + kb);
            if (XRELU) {
#pragma unroll
              for (int j = 0; j < 8; ++j) xv[j] = (xv[j] & 0x8000u) ? (ushort)0 : xv[j];
            }
          } else {
            const float* xp = (const float*)Xv + grow * K + k0 + kb;
            float4 va = *(const float4*)xp;
            float4 vb = *(const float4*)(xp + 4);
            if (XRELU) {
              va.x = fmaxf(va.x, 0.f); va.y = fmaxf(va.y, 0.f);
              va.z = fmaxf(va.z, 0.f); va.w = fmaxf(va.w, 0.f);
              vb.x = fmaxf(vb.x, 0.f); vb.y = fmaxf(vb.y, 0.f);
              vb.z = fmaxf(vb.z, 0.f); vb.w = fmaxf(vb.w, 0.f);
            }
            xv[0] = f2bf(va.x); xv[1] = f2bf(va.y); xv[2] = f2bf(va.z); xv[3] = f2bf(va.w);
            xv[4] = f2bf(vb.x); xv[5] = f2bf(vb.y); xv[6] = f2bf(vb.z); xv[7] = f2bf(vb.w);
          }
        } else {
#pragma unroll
          for (int j = 0; j < 8; ++j) xv[j] = 0;
        }
        *(u16x8*)&Xs[row * XPITCH + kb] = xv;
        *(u16x8*)&Ws[row * XPITCH + kb] = *(const u16x8*)(WT + (ll)row * K + k0 + kb);
      }
      __syncthreads();
#pragma unroll
      for (int kk = 0; kk < BK; kk += 32) {
        const int krow = kk + ((lane >> 4) << 3);
        bf16x8 af[4], bfr[4];
#pragma unroll
        for (int mi = 0; mi < 4; ++mi)
          af[mi] = *(const bf16x8*)&Xs[(wm + mi * 16 + (lane & 15)) * XPITCH + krow];
#pragma unroll
        for (int ni = 0; ni < 4; ++ni)
          bfr[ni] = *(const bf16x8*)&Ws[(wn + ni * 16 + (lane & 15)) * XPITCH + krow];
#pragma unroll
        for (int mi = 0; mi < 4; ++mi)
#pragma unroll
          for (int ni = 0; ni < 4; ++ni)
            acc[mi][ni] = __builtin_amdgcn_mfma_f32_16x16x32_bf16(af[mi], bfr[ni],
                                                                  acc[mi][ni], 0, 0, 0);
      }
    }
  }

  __syncthreads();  // in-place safety + LDS reuse

  {
    const int colb = wn + (lane & 15);
    const int rsub = (lane >> 4) << 2;
#pragma unroll
    for (int ni = 0; ni < 4; ++ni) {
      int col = colb + ni * 16;
      float bv = a.bias ? a.bias[col] : 0.f;
#pragma unroll
      for (int mi = 0; mi < 4; ++mi) {
        int row0 = wm + mi * 16 + rsub;
#pragma unroll
        for (int j = 0; j < 4; ++j)
          sbuf[(row0 + j) * CPITCH + col] = f2bf(acc[mi][ni][j] + bv);
      }
    }
  }
  __syncthreads();
  {
    int lrow = t >> 1;
    int half = t & 1;
    ll grow = rbase + lrow;
    if (grow < M) {
      const ushort* src = &sbuf[lrow * CPITCH + half * 64];
      ushort* dst = (ushort*)a.out + grow * 128 + half * 64;
#pragma unroll
      for (int k = 0; k < 8; ++k)
        *(u16x8*)(dst + k * 8) = *(const u16x8*)(src + k * 8);
    }
  }
}

// ---------------- launch ----------------
extern "C" void kernel_launch(void* const* d_in, const int* in_sizes, int n_in,
                              void* d_out, int out_size, void* d_ws, size_t ws_size,
                              hipStream_t stream) {
  const float* xm = (const float*)d_in[0];
  const float* xc = (const float*)d_in[1];
  const float* xa = (const float*)d_in[2];
  const int* src_cm = (const int*)d_in[3];
  const int* dst_cm = (const int*)d_in[4];
  const int* src_am = (const int*)d_in[5];
  const int* dst_am = (const int*)d_in[6];
  const float* Wl_cm_0 = (const float*)d_in[7];
  const float* Wr_cm_0 = (const float*)d_in[8];
  const float* b_cm_0  = (const float*)d_in[9];
  const float* Wl_am_0 = (const float*)d_in[10];
  const float* Wr_am_0 = (const float*)d_in[11];
  const float* b_am_0  = (const float*)d_in[12];
  const float* Wl_mc_0 = (const float*)d_in[13];
  const float* Wr_mc_0 = (const float*)d_in[14];
  const float* b_mc_0  = (const float*)d_in[15];
  const float* Wl_ma_0 = (const float*)d_in[16];
  const float* Wr_ma_0 = (const float*)d_in[17];
  const float* b_ma_0  = (const float*)d_in[18];
  const float* Wl_cm_1 = (const float*)d_in[19];
  const float* Wr_cm_1 = (const float*)d_in[20];
  const float* b_cm_1  = (const float*)d_in[21];
  const float* Wl_am_1 = (const float*)d_in[22];
  const float* Wr_am_1 = (const float*)d_in[23];
  const float* b_am_1  = (const float*)d_in[24];
  const float* lin_W   = (const float*)d_in[31];
  const float* lin_b   = (const float*)d_in[32];

  const int NM = in_sizes[0] / 128;
  const int NC = in_sizes[1] / 64;
  const int NA = in_sizes[2] / 64;
  const int E  = in_sizes[3];
  const int SMAX = (NC > NA) ? NC : NA;

  // ---- workspace layout (float units) ----
  float* base = (float*)d_ws;
  size_t o = 0;
  ushort* A = (ushort*)(base + o); o += (size_t)NM * 64;   // movie features bf16
  ushort* xmh = (ushort*)(base + o); o += (size_t)NM * 64; // xm as bf16
  float* S = base + o; o += (size_t)SMAX * 128;            // S1h/S2h; ranks early
  ushort* S3h = (ushort*)(base + o); o += (size_t)SMAX * 64;  // xc/B transform out
  ushort* S4h = (ushort*)(base + o); o += (size_t)SMAX * 64;  // xa/C transform out
  ushort* B = (ushort*)(base + o); o += (size_t)NC * 64;   // xc1 pre-relu, bf16
  ushort* C = (ushort*)(base + o); o += (size_t)NA * 64;   // xa1 pre-relu, bf16
  int* cnt_m_cm = (int*)(base + o); o += NM;               // contiguous cnt block
  int* cnt_m_am = (int*)(base + o); o += NM;
  int* cnt_c    = (int*)(base + o); o += NC;
  int* cnt_a    = (int*)(base + o); o += NA;
  float* rinv_m_cm = base + o; o += NM;                    // rinv block (same order)
  float* rinv_m_am = base + o; o += NM;
  float* rinv_c    = base + o; o += NC;
  float* rinv_a    = base + o; o += NA;
  int* rp_m_cm = (int*)(base + o); o += NM + 1;
  int* rp_m_am = (int*)(base + o); o += NM + 1;
  int* rp_c    = (int*)(base + o); o += NC + 1;
  int* rp_a    = (int*)(base + o); o += NA + 1;
  int* pm_m_cm = (int*)(base + o); o += E;
  int* pm_m_am = (int*)(base + o); o += E;
  int* pm_c    = (int*)(base + o); o += E;
  int* pm_a    = (int*)(base + o); o += E;
  int* bsum    = (int*)(base + o); o += 4096;
  float* b0c  = base + o; o += 128;
  float* b1c  = base + o; o += 128;
  ushort* WT_r0   = (ushort*)(base + o); o += 8192;
  ushort* WT_r1   = (ushort*)(base + o); o += 8192;
  ushort* WT_mc0l = (ushort*)(base + o); o += 8192;
  ushort* WT_ma0l = (ushort*)(base + o); o += 8192;
  ushort* WT_cm1  = (ushort*)(base + o); o += 8192;
  ushort* WT_am1  = (ushort*)(base + o); o += 8192;
  ushort* WT_mc0r = (ushort*)(base + o); o += 4096;
  ushort* WT_ma0r = (ushort*)(base + o); o += 4096;
  ushort* WT_cm0  = (ushort*)(base + o); o += 4096;
  ushort* WT_am0  = (ushort*)(base + o); o += 4096;

  if (ws_size < o * sizeof(float)) return;  // diagnostic guard

  // ranks overlay S (S written only after fill completes)
  int* rk_m_cm = (int*)S;
  int* rk_c    = rk_m_cm + E;
  int* rk_m_am = rk_m_cm + 2 * E;
  int* rk_a    = rk_m_cm + 3 * E;
  ushort* S1h = (ushort*)S;
  ushort* S2h = S1h + (size_t)SMAX * 128;

  float* outf = (float*)d_out;
  const int g2E = (2 * E + TPB - 1) / TPB;
  const int nbm = (NM + TPB - 1) / TPB;
  const int nbc = (NC + TPB - 1) / TPB;
  const int nba = (NA + TPB - 1) / TPB;
  const int nbtot = 2 * nbm + nbc + nba;
  const int nodes_total = 2 * NM + NC + NA;
  const ll n8 = (ll)NM * 16;
  const int gConv = (int)((n8 + TPB - 1) / TPB);

  PJobs J;
  J.a[0] = Wr_cm_0; J.bavg[0] = Wr_am_0; J.out[0] = WT_r0;
  J.a[1] = Wr_cm_1; J.bavg[1] = Wr_am_1; J.out[1] = WT_r1;
  J.a[2] = Wl_mc_0; J.bavg[2] = nullptr; J.out[2] = WT_mc0l;
  J.a[3] = Wl_ma_0; J.bavg[3] = nullptr; J.out[3] = WT_ma0l;
  J.a[4] = Wl_cm_1; J.bavg[4] = nullptr; J.out[4] = WT_cm1;
  J.a[5] = Wl_am_1; J.bavg[5] = nullptr; J.out[5] = WT_am1;
  J.a[6] = Wr_mc_0; J.bavg[6] = nullptr; J.out[6] = WT_mc0r;
  J.a[7] = Wr_ma_0; J.bavg[7] = nullptr; J.out[7] = WT_ma0r;
  J.a[8] = Wl_cm_0; J.bavg[8] = nullptr; J.out[8] = WT_cm0;
  J.a[9] = Wl_am_0; J.bavg[9] = nullptr; J.out[9] = WT_am0;
  J.ba[0] = b_cm_0; J.bb[0] = b_am_0; J.bo[0] = b0c;
  J.ba[1] = b_cm_1; J.bb[1] = b_am_1; J.bo[1] = b1c;

  // 1) mega1: NT convert || counts+ranks || weight prep
  hipMemsetAsync(cnt_m_cm, 0, sizeof(int) * (size_t)nodes_total, stream);
  mega1_k<<<gConv + g2E + 513, TPB, 0, stream>>>(
      xm, xmh, n8, gConv, src_cm, dst_cm, src_am, dst_am, E, g2E,
      cnt_m_cm, cnt_m_am, cnt_c, cnt_a, rk_m_cm, rk_c, rk_m_am, rk_a, J);

  // 2) blocksum || rinv, scan, finalize
  {
    int gR = (nodes_total + TPB - 1) / TPB;
    bsum_rinv_k<<<nbtot + gR, TPB, 0, stream>>>(cnt_m_cm, NM, cnt_m_am, NM,
                                                cnt_c, NC, cnt_a, NA, bsum,
                                                rinv_m_cm, 2 * NM, nodes_total, nbtot);
  }
  scan_all_k<<<4, TPB, 0, stream>>>(bsum, NM, NM, NC, NA);
  finalize_all_k<<<nbtot, TPB, 0, stream>>>(cnt_m_cm, NM, rp_m_cm, cnt_m_am, NM, rp_m_am,
                                            cnt_c, NC, rp_c, cnt_a, NA, rp_a, bsum);

  const int gM = (NM + 127) / 128;
  const int gC = (NC + 127) / 128;
  const int gA = (NA + 127) / 128;
  const int gnM = (NM + 15) / 16;
  const int gwc = (NC + 15) / 16;
  const int gwa = (NA + 15) / 16;
  CArgs Z = {};
  FArgs F = {src_cm, dst_cm, src_am, dst_am, E,
             rp_m_cm, rp_m_am, rp_c, rp_a,
             rk_m_cm, rk_c, rk_m_am, rk_a,
             pm_m_cm, pm_m_am, pm_c, pm_a};
  FArgs F0 = {};

  // 3) mega2: fill || movie-Wr0 GEMM || xc/xa transforms (CSR-independent MFMA)
  {
    CArgs am = {xmh, WT_r0, 128, 1, nullptr, nullptr, 0, 0, 1, b0c, A, NM, gM};
    CArgs tc = {xc, WT_cm0, 64, 0, nullptr, nullptr, 0, 0, 1, nullptr, S3h, NC, gC};
    CArgs ta = {xa, WT_am0, 64, 0, nullptr, nullptr, 0, 0, 1, nullptr, S4h, NA, gA};
    mega2_k<false><<<g2E + gM + gC + gA, TPB, 0, stream>>>(F, g2E, am, tc, ta, Z, Z);
  }

  // ---- layer 0: crew & cast movie-mean gathers, then their combines ----
  gatherw2_k<<<gwc + gwa, TPB, 0, stream>>>(xmh, rp_c, pm_c, rinv_c, NC, S1h,
                                            rp_a, pm_a, rinv_a, NA, S2h, gwc);
  {
    CArgs ac = {S1h, WT_mc0l, 128, 1, xc, WT_mc0r, 64, 0, 2, b_mc_0, B, NC, gC};
    CArgs aa = {S2h, WT_ma0l, 128, 1, xa, WT_ma0r, 64, 0, 2, b_ma_0, C, NA, gA};
    mega2_k<false><<<gC + gA, TPB, 0, stream>>>(F0, 0, ac, aa, Z, Z, Z);
  }
  gather2_k<<<gnM, TPB, 0, stream>>>(S3h, S4h, rp_m_cm, pm_m_cm, rinv_m_cm,
                                     rp_m_am, pm_m_am, rinv_m_am, NM, A);
  // A = xm1 pre-relu (bf16)

  // ---- layer 1: movie self-GEMM (in-place) + B/C transforms ----
  {
    CArgs am = {A, WT_r1, 128, 1, nullptr, nullptr, 0, 0, 1, b1c, A, NM, gM};
    CArgs ac = {B, WT_cm1, 128, 1, nullptr, nullptr, 0, 0, 1, nullptr, S3h, NC, gC};
    CArgs aa = {C, WT_am1, 128, 1, nullptr, nullptr, 0, 0, 1, nullptr, S4h, NA, gA};
    mega2_k<true><<<gM + gC + gA, TPB, 0, stream>>>(F0, 0, am, ac, aa, Z, Z);
  }
  gather2_k<<<gnM, TPB, 0, stream>>>(S3h, S4h, rp_m_cm, pm_m_cm, rinv_m_cm,
                                     rp_m_am, pm_m_am, rinv_m_am, NM, A);
  // A = xm2 pre-relu (bf16)

  // ---- final linear ----
  final_k<<<(NM + TPB - 1) / TPB, TPB, 0, stream>>>(A, lin_W, lin_b, outf, NM);
}

// Round 14
// 560.425 us; speedup vs baseline: 1.0276x; 1.0276x over previous
//
#include <hip/hip_runtime.h>

#define TPB 256
typedef unsigned int uint;
typedef unsigned short ushort;
typedef long long ll;
typedef __attribute__((ext_vector_type(8))) short bf16x8;
typedef __attribute__((ext_vector_type(8))) ushort u16x8;
typedef __attribute__((ext_vector_type(4))) float f32x4;

__device__ __forceinline__ float bf2f(ushort h) {
  return __uint_as_float(((uint)h) << 16);
}
__device__ __forceinline__ ushort f2bf(float f) {
  uint u = __float_as_uint(f);
  u += 0x7fffu + ((u >> 16) & 1u);
  return (ushort)(u >> 16);
}

// ---------------- one-dispatch prep payload ----------------
struct PJobs {
  const float* a[10];
  const float* bavg[10];
  ushort* out[10];
  const float* ba[2];
  const float* bb[2];
  float* bo[2];
};

// ------- mega1: convert (BW, non-temporal) || rank (atomic-latency) || prep ---------
// NT loads/stores on the convert branch keep the 2.4MB cnt arrays L2-resident
// so rank's atomics stay L2-speed instead of HBM RMW. (Confirmed r13: 150->127us)
__global__ __launch_bounds__(TPB) void mega1_k(
    const float* __restrict__ xm, ushort* __restrict__ xmh, ll n8, int gConv,
    const int* __restrict__ src_cm, const int* __restrict__ dst_cm,
    const int* __restrict__ src_am, const int* __restrict__ dst_am, int E, int g2E,
    int* __restrict__ cnt_m_cm, int* __restrict__ cnt_m_am,
    int* __restrict__ cnt_c, int* __restrict__ cnt_a,
    int* __restrict__ rk_m_cm, int* __restrict__ rk_c,
    int* __restrict__ rk_m_am, int* __restrict__ rk_a,
    PJobs J) {
  int b = blockIdx.x;
  int t = threadIdx.x;
  if (b < gConv) {  // xm f32 -> bf16 (non-temporal: bypass L2)
    ll i = (ll)b * TPB + t;
    if (i >= n8) return;
    const f32x4* p = (const f32x4*)(xm + i * 8);
    f32x4 a = __builtin_nontemporal_load(p);
    f32x4 bb = __builtin_nontemporal_load(p + 1);
    u16x8 v;
    v[0] = f2bf(a[0]); v[1] = f2bf(a[1]); v[2] = f2bf(a[2]); v[3] = f2bf(a[3]);
    v[4] = f2bf(bb[0]); v[5] = f2bf(bb[1]); v[6] = f2bf(bb[2]); v[7] = f2bf(bb[3]);
    __builtin_nontemporal_store(v, (u16x8*)&xmh[i * 8]);
    return;
  }
  b -= gConv;
  if (b < g2E) {  // counts + per-edge local rank (one atomic pass)
    int i = b * TPB + t;
    if (i < E) {
      rk_m_cm[i] = atomicAdd(&cnt_m_cm[dst_cm[i]], 1);
      rk_c[i]    = atomicAdd(&cnt_c[src_cm[i]], 1);
    } else if (i < 2 * E) {
      int e = i - E;
      rk_m_am[e] = atomicAdd(&cnt_m_am[dst_am[e]], 1);
      rk_a[e]    = atomicAdd(&cnt_a[src_am[e]], 1);
    }
    return;
  }
  b -= g2E;  // prep: 10 weight transposes + 2 bias averages (513 blocks)
  if (b == 512) {
    if (t < 128) J.bo[0][t] = 0.5f * (J.ba[0][t] + J.bb[0][t]);
    else if (t < 256) J.bo[1][t - 128] = 0.5f * (J.ba[1][t - 128] + J.bb[1][t - 128]);
    return;
  }
  int job, idx, K;
  if (b < 384) { job = b >> 6; idx = ((b & 63) << 8) | t; K = 128; }
  else { int bb2 = b - 384; job = 6 + (bb2 >> 5); idx = ((bb2 & 31) << 8) | t; K = 64; }
  int col = idx / K, k = idx - col * K;
  float v = J.a[job][k * 128 + col];
  if (J.bavg[job]) v = 0.5f * (v + J.bavg[job][k * 128 + col]);
  J.out[job][idx] = f2bf(v);
}

// ---------------- CSR build helpers ----------------
__device__ __forceinline__ void rel_map(int b, int nb0, int nb1, int nb2, int nb3,
                                        int& r, int& lb) {
  if (b < nb0) { r = 0; lb = b; }
  else if (b < nb0 + nb1) { r = 1; lb = b - nb0; }
  else if (b < nb0 + nb1 + nb2) { r = 2; lb = b - nb0 - nb1; }
  else { r = 3; lb = b - nb0 - nb1 - nb2; }
}

__global__ __launch_bounds__(TPB) void bsum_rinv_k(
    const int* __restrict__ c0, int n0, const int* __restrict__ c1, int n1,
    const int* __restrict__ c2, int n2, const int* __restrict__ c3, int n3,
    int* __restrict__ bsum, float* __restrict__ rinv, int nm2, int total, int nbtot) {
  __shared__ int lds[TPB];
  int b = blockIdx.x;
  int t = threadIdx.x;
  if (b >= nbtot) {  // rinv branch (cnt block is contiguous starting at c0)
    int i = (b - nbtot) * TPB + t;
    if (i < total) {
      float scale = (i < nm2) ? 0.5f : 1.0f;
      rinv[i] = scale / fmaxf((float)c0[i], 1.0f);
    }
    return;
  }
  int nb0 = (n0 + TPB - 1) / TPB, nb1 = (n1 + TPB - 1) / TPB;
  int nb2 = (n2 + TPB - 1) / TPB, nb3 = (n3 + TPB - 1) / TPB;
  int r, lb;
  rel_map(b, nb0, nb1, nb2, nb3, r, lb);
  const int* cnt = (r == 0) ? c0 : (r == 1) ? c1 : (r == 2) ? c2 : c3;
  int n = (r == 0) ? n0 : (r == 1) ? n1 : (r == 2) ? n2 : n3;
  int i = lb * TPB + t;
  lds[t] = (i < n) ? cnt[i] : 0;
  __syncthreads();
  for (int off = 128; off > 0; off >>= 1) {
    if (t < off) lds[t] += lds[t + off];
    __syncthreads();
  }
  if (t == 0) bsum[r * 1024 + lb] = lds[0];
}

__global__ __launch_bounds__(TPB) void scan_all_k(int* __restrict__ bsum,
                                                  int n0, int n1, int n2, int n3) {
  __shared__ int lds[TPB];
  int r = blockIdx.x;
  int n = (r == 0) ? n0 : (r == 1) ? n1 : (r == 2) ? n2 : n3;
  int nb = (n + TPB - 1) / TPB;
  int* bs = bsum + r * 1024;
  int t = threadIdx.x;
  int offset = 0;
  for (int base = 0; base < nb; base += TPB) {
    int v = (base + t < nb) ? bs[base + t] : 0;
    lds[t] = v;
    __syncthreads();
    for (int off = 1; off < TPB; off <<= 1) {
      int add = (t >= off) ? lds[t - off] : 0;
      __syncthreads();
      lds[t] += add;
      __syncthreads();
    }
    int incl = lds[t];
    if (base + t < nb) bs[base + t] = offset + incl - v;
    int tot = lds[TPB - 1];
    __syncthreads();
    offset += tot;
  }
}

__global__ __launch_bounds__(TPB) void finalize_all_k(
    const int* __restrict__ c0, int n0, int* __restrict__ rp0,
    const int* __restrict__ c1, int n1, int* __restrict__ rp1,
    const int* __restrict__ c2, int n2, int* __restrict__ rp2,
    const int* __restrict__ c3, int n3, int* __restrict__ rp3,
    const int* __restrict__ bsum) {
  __shared__ int lds[TPB];
  int nb0 = (n0 + TPB - 1) / TPB, nb1 = (n1 + TPB - 1) / TPB;
  int nb2 = (n2 + TPB - 1) / TPB, nb3 = (n3 + TPB - 1) / TPB;
  int r, lb;
  rel_map(blockIdx.x, nb0, nb1, nb2, nb3, r, lb);
  const int* cnt = (r == 0) ? c0 : (r == 1) ? c1 : (r == 2) ? c2 : c3;
  int* rowptr = (r == 0) ? rp0 : (r == 1) ? rp1 : (r == 2) ? rp2 : rp3;
  int n = (r == 0) ? n0 : (r == 1) ? n1 : (r == 2) ? n2 : n3;
  int t = threadIdx.x;
  int i = lb * TPB + t;
  int v = (i < n) ? cnt[i] : 0;
  lds[t] = v;
  __syncthreads();
  for (int off = 1; off < TPB; off <<= 1) {
    int add = (t >= off) ? lds[t - off] : 0;
    __syncthreads();
    lds[t] += add;
    __syncthreads();
  }
  int ex = lds[t] - v + bsum[r * 1024 + lb];
  if (i < n) {
    rowptr[i] = ex;
    if (i == n - 1) rowptr[n] = ex + v;
  }
}

// fill via precomputed ranks: NO atomics (standalone: full occupancy, no LDS)
__global__ __launch_bounds__(TPB) void fillr_k(const int* __restrict__ src_cm,
                                               const int* __restrict__ dst_cm,
                                               const int* __restrict__ src_am,
                                               const int* __restrict__ dst_am, int E,
                                               const int* __restrict__ rp_m_cm,
                                               const int* __restrict__ rp_m_am,
                                               const int* __restrict__ rp_c,
                                               const int* __restrict__ rp_a,
                                               const int* __restrict__ rk_m_cm,
                                               const int* __restrict__ rk_c,
                                               const int* __restrict__ rk_m_am,
                                               const int* __restrict__ rk_a,
                                               int* __restrict__ pm_m_cm,
                                               int* __restrict__ pm_m_am,
                                               int* __restrict__ pm_c,
                                               int* __restrict__ pm_a) {
  int i = blockIdx.x * blockDim.x + threadIdx.x;
  if (i < E) {
    int s = src_cm[i], d = dst_cm[i];
    pm_m_cm[rp_m_cm[d] + rk_m_cm[i]] = s;
    pm_c[rp_c[s] + rk_c[i]] = d;
  } else if (i < 2 * E) {
    int e = i - E;
    int s = src_am[e], d = dst_am[e];
    pm_m_am[rp_m_am[d] + rk_m_am[e]] = s;
    pm_a[rp_a[s] + rk_a[e]] = d;
  }
}

// -------- merged crew+cast gather, 16 lanes/row, 2-way unrolled degree loop ---------
__global__ __launch_bounds__(TPB) void gatherw2_k(
    const ushort* __restrict__ xmh,
    const int* __restrict__ rp1, const int* __restrict__ pm1,
    const float* __restrict__ ri1, int N1, ushort* __restrict__ o1,
    const int* __restrict__ rp2, const int* __restrict__ pm2,
    const float* __restrict__ ri2, int N2, ushort* __restrict__ o2, int g1) {
  int b = blockIdx.x;
  const int* rowptr; const int* perm; const float* rinv; int N; ushort* out;
  int lb;
  if (b < g1) { rowptr = rp1; perm = pm1; rinv = ri1; N = N1; out = o1; lb = b; }
  else { rowptr = rp2; perm = pm2; rinv = ri2; N = N2; out = o2; lb = b - g1; }
  int nid = lb * 16 + (threadIdx.x >> 4);
  if (nid >= N) return;
  int d = (threadIdx.x & 15) << 3;
  int j = rowptr[nid], e = rowptr[nid + 1];
  float aA[8] = {0.f}, aB[8] = {0.f};
  for (; j + 1 < e; j += 2) {
    u16x8 v0 = *(const u16x8*)&xmh[((ll)perm[j] << 7) + d];
    u16x8 v1 = *(const u16x8*)&xmh[((ll)perm[j + 1] << 7) + d];
#pragma unroll
    for (int k = 0; k < 8; ++k) { aA[k] += bf2f(v0[k]); aB[k] += bf2f(v1[k]); }
  }
  if (j < e) {
    u16x8 v0 = *(const u16x8*)&xmh[((ll)perm[j] << 7) + d];
#pragma unroll
    for (int k = 0; k < 8; ++k) aA[k] += bf2f(v0[k]);
  }
  float r = rinv[nid];
  u16x8 o;
#pragma unroll
  for (int k = 0; k < 8; ++k) o[k] = f2bf((aA[k] + aB[k]) * r);
  *(u16x8*)&out[((ll)nid << 7) + d] = o;
}

// -------- dual-CSR gather into bf16 A (single RMW), 2-way unrolled ------------------
__global__ __launch_bounds__(TPB) void gather2_k(
    const ushort* __restrict__ s1, const ushort* __restrict__ s2,
    const int* __restrict__ rp1, const int* __restrict__ pm1, const float* __restrict__ ri1,
    const int* __restrict__ rp2, const int* __restrict__ pm2, const float* __restrict__ ri2,
    int N, ushort* __restrict__ out) {
  int nid = blockIdx.x * 16 + (threadIdx.x >> 4);
  if (nid >= N) return;
  int d = (threadIdx.x & 15) << 3;
  float aA[8] = {0.f}, aB[8] = {0.f};
  {
    int j = rp1[nid], e = rp1[nid + 1];
    for (; j + 1 < e; j += 2) {
      u16x8 v0 = *(const u16x8*)&s1[((ll)pm1[j] << 7) + d];
      u16x8 v1 = *(const u16x8*)&s1[((ll)pm1[j + 1] << 7) + d];
#pragma unroll
      for (int k = 0; k < 8; ++k) { aA[k] += bf2f(v0[k]); aB[k] += bf2f(v1[k]); }
    }
    if (j < e) {
      u16x8 v0 = *(const u16x8*)&s1[((ll)pm1[j] << 7) + d];
#pragma unroll
      for (int k = 0; k < 8; ++k) aA[k] += bf2f(v0[k]);
    }
  }
  float r1 = ri1[nid];
  float res[8];
#pragma unroll
  for (int k = 0; k < 8; ++k) res[k] = (aA[k] + aB[k]) * r1;
  float bA[8] = {0.f}, bB[8] = {0.f};
  {
    int j = rp2[nid], e = rp2[nid + 1];
    for (; j + 1 < e; j += 2) {
      u16x8 v0 = *(const u16x8*)&s2[((ll)pm2[j] << 7) + d];
      u16x8 v1 = *(const u16x8*)&s2[((ll)pm2[j + 1] << 7) + d];
#pragma unroll
      for (int k = 0; k < 8; ++k) { bA[k] += bf2f(v0[k]); bB[k] += bf2f(v1[k]); }
    }
    if (j < e) {
      u16x8 v0 = *(const u16x8*)&s2[((ll)pm2[j] << 7) + d];
#pragma unroll
      for (int k = 0; k < 8; ++k) bA[k] += bf2f(v0[k]);
    }
  }
  float r2 = ri2[nid];
  ushort* p = &out[((ll)nid << 7) + d];
  u16x8 cur = *(u16x8*)p;
  u16x8 o;
#pragma unroll
  for (int k = 0; k < 8; ++k)
    o[k] = f2bf(bf2f(cur[k]) + res[k] + (bA[k] + bB[k]) * r2);
  *(u16x8*)p = o;
}

// ---------------- final linear: relu(X bf16) (M x 128) @ (128 x 16) + b -------------
__global__ __launch_bounds__(TPB) void final_k(const ushort* __restrict__ X,
                                               const float* __restrict__ W,
                                               const float* __restrict__ b,
                                               float* __restrict__ out, int M) {
  __shared__ float lw[128 * 16];
  __shared__ float lb[16];
  int t = threadIdx.x;
  for (int i = t; i < 2048; i += TPB) lw[i] = W[i];
  if (t < 16) lb[t] = b[t];
  __syncthreads();
  ll row = (ll)blockIdx.x * TPB + t;
  if (row >= M) return;
  float acc[16];
#pragma unroll
  for (int c = 0; c < 16; ++c) acc[c] = lb[c];
  const ushort* xr = &X[row * 128];
  for (int k = 0; k < 128; k += 8) {
    u16x8 xv = *(const u16x8*)&xr[k];
#pragma unroll
    for (int j = 0; j < 8; ++j) {
      float xs = fmaxf(bf2f(xv[j]), 0.f);
#pragma unroll
      for (int c = 0; c < 16; ++c) acc[c] = fmaf(xs, lw[(k + j) * 16 + c], acc[c]);
    }
  }
#pragma unroll
  for (int c = 0; c < 16; c += 4) {
    float4 o; o.x = acc[c]; o.y = acc[c + 1]; o.z = acc[c + 2]; o.w = acc[c + 3];
    *(float4*)&out[row * 16 + c] = o;
  }
}

// ---------------- MFMA multi-segment GEMM (+bias), N=128, 5-problem -----------------
// bf16 output; epilogue staged through LDS for coalesced 16B stores.
#define BK 64
#define XPITCH 72
#define CPITCH 132
struct CArgs {
  const void* X0; const ushort* WT0; int K0; int xb0;
  const void* X1; const ushort* WT1; int K1; int xb1;
  int nseg; const float* bias; void* out; int M; int nblk;
};

template <bool XRELU>
__global__ __launch_bounds__(TPB) void mfma5_k(CArgs a0, CArgs a1, CArgs a2,
                                               CArgs a3, CArgs a4) {
  const int bx = blockIdx.x;
  const int o0 = a0.nblk, o1 = o0 + a1.nblk, o2 = o1 + a2.nblk, o3 = o2 + a3.nblk;
  const CArgs& a = (bx < o0) ? a0 : (bx < o1) ? a1 : (bx < o2) ? a2
                   : (bx < o3) ? a3 : a4;
  const int blk = bx - ((bx < o0) ? 0 : (bx < o1) ? o0 : (bx < o2) ? o1
                        : (bx < o3) ? o2 : o3);

  __shared__ ushort sbuf[2 * 128 * XPITCH];  // Xs/Ws in K-loop; C-tile in epilogue
  ushort* Xs = sbuf;
  ushort* Ws = sbuf + 128 * XPITCH;
  const int t = threadIdx.x;
  const int lane = t & 63;
  const int wid = t >> 6;
  const int wm = (wid >> 1) << 6;
  const int wn = (wid & 1) << 6;
  const ll rbase = (ll)blk * 128;
  const int M = a.M;

  f32x4 acc[4][4];
#pragma unroll
  for (int mi = 0; mi < 4; ++mi)
#pragma unroll
    for (int ni = 0; ni < 4; ++ni) acc[mi][ni] = (f32x4){0.f, 0.f, 0.f, 0.f};

  for (int s = 0; s < a.nseg; ++s) {
    const void* Xv = s ? a.X1 : a.X0;
    const ushort* WT = s ? a.WT1 : a.WT0;
    const int K = s ? a.K1 : a.K0;
    const int xb = s ? a.xb1 : a.xb0;
    for (int k0 = 0; k0 < K; k0 += BK) {
      __syncthreads();
#pragma unroll
      for (int i = 0; i < 4; ++i) {
        int idx8 = t + i * TPB;
        int row = idx8 >> 3;
        int kb = (idx8 & 7) << 3;
        u16x8 xv;
        ll grow = rbase + row;
        if (grow < M) {
          if (xb) {
            xv = *(const u16x8*)((const ushort*)Xv + grow * K + k0 + kb);
            if (XRELU) {
#pragma unroll
              for (int j = 0; j < 8; ++j) xv[j] = (xv[j] & 0x8000u) ? (ushort)0 : xv[j];
            }
          } else {
            const float* xp = (const float*)Xv + grow * K + k0 + kb;
            float4 va = *(const float4*)xp;
            float4 vb = *(const float4*)(xp + 4);
            if (XRELU) {
              va.x = fmaxf(va.x, 0.f); va.y = fmaxf(va.y, 0.f);
              va.z = fmaxf(va.z, 0.f); va.w = fmaxf(va.w, 0.f);
              vb.x = fmaxf(vb.x, 0.f); vb.y = fmaxf(vb.y, 0.f);
              vb.z = fmaxf(vb.z, 0.f); vb.w = fmaxf(vb.w, 0.f);
            }
            xv[0] = f2bf(va.x); xv[1] = f2bf(va.y); xv[2] = f2bf(va.z); xv[3] = f2bf(va.w);
            xv[4] = f2bf(vb.x); xv[5] = f2bf(vb.y); xv[6] = f2bf(vb.z); xv[7] = f2bf(vb.w);
          }
        } else {
#pragma unroll
          for (int j = 0; j < 8; ++j) xv[j] = 0;
        }
        *(u16x8*)&Xs[row * XPITCH + kb] = xv;
        *(u16x8*)&Ws[row * XPITCH + kb] = *(const u16x8*)(WT + (ll)row * K + k0 + kb);
      }
      __syncthreads();
#pragma unroll
      for (int kk = 0; kk < BK; kk += 32) {
        const int krow = kk + ((lane >> 4) << 3);
        bf16x8 af[4], bfr[4];
#pragma unroll
        for (int mi = 0; mi < 4; ++mi)
          af[mi] = *(const bf16x8*)&Xs[(wm + mi * 16 + (lane & 15)) * XPITCH + krow];
#pragma unroll
        for (int ni = 0; ni < 4; ++ni)
          bfr[ni] = *(const bf16x8*)&Ws[(wn + ni * 16 + (lane & 15)) * XPITCH + krow];
#pragma unroll
        for (int mi = 0; mi < 4; ++mi)
#pragma unroll
          for (int ni = 0; ni < 4; ++ni)
            acc[mi][ni] = __builtin_amdgcn_mfma_f32_16x16x32_bf16(af[mi], bfr[ni],
                                                                  acc[mi][ni], 0, 0, 0);
      }
    }
  }

  __syncthreads();  // in-place safety + LDS reuse

  {
    const int colb = wn + (lane & 15);
    const int rsub = (lane >> 4) << 2;
#pragma unroll
    for (int ni = 0; ni < 4; ++ni) {
      int col = colb + ni * 16;
      float bv = a.bias ? a.bias[col] : 0.f;
#pragma unroll
      for (int mi = 0; mi < 4; ++mi) {
        int row0 = wm + mi * 16 + rsub;
#pragma unroll
        for (int j = 0; j < 4; ++j)
          sbuf[(row0 + j) * CPITCH + col] = f2bf(acc[mi][ni][j] + bv);
      }
    }
  }
  __syncthreads();
  {
    int lrow = t >> 1;
    int half = t & 1;
    ll grow = rbase + lrow;
    if (grow < M) {
      const ushort* src = &sbuf[lrow * CPITCH + half * 64];
      ushort* dst = (ushort*)a.out + grow * 128 + half * 64;
#pragma unroll
      for (int k = 0; k < 8; ++k)
        *(u16x8*)(dst + k * 8) = *(const u16x8*)(src + k * 8);
    }
  }
}

// ---------------- launch ----------------
extern "C" void kernel_launch(void* const* d_in, const int* in_sizes, int n_in,
                              void* d_out, int out_size, void* d_ws, size_t ws_size,
                              hipStream_t stream) {
  const float* xm = (const float*)d_in[0];
  const float* xc = (const float*)d_in[1];
  const float* xa = (const float*)d_in[2];
  const int* src_cm = (const int*)d_in[3];
  const int* dst_cm = (const int*)d_in[4];
  const int* src_am = (const int*)d_in[5];
  const int* dst_am = (const int*)d_in[6];
  const float* Wl_cm_0 = (const float*)d_in[7];
  const float* Wr_cm_0 = (const float*)d_in[8];
  const float* b_cm_0  = (const float*)d_in[9];
  const float* Wl_am_0 = (const float*)d_in[10];
  const float* Wr_am_0 = (const float*)d_in[11];
  const float* b_am_0  = (const float*)d_in[12];
  const float* Wl_mc_0 = (const float*)d_in[13];
  const float* Wr_mc_0 = (const float*)d_in[14];
  const float* b_mc_0  = (const float*)d_in[15];
  const float* Wl_ma_0 = (const float*)d_in[16];
  const float* Wr_ma_0 = (const float*)d_in[17];
  const float* b_ma_0  = (const float*)d_in[18];
  const float* Wl_cm_1 = (const float*)d_in[19];
  const float* Wr_cm_1 = (const float*)d_in[20];
  const float* b_cm_1  = (const float*)d_in[21];
  const float* Wl_am_1 = (const float*)d_in[22];
  const float* Wr_am_1 = (const float*)d_in[23];
  const float* b_am_1  = (const float*)d_in[24];
  const float* lin_W   = (const float*)d_in[31];
  const float* lin_b   = (const float*)d_in[32];

  const int NM = in_sizes[0] / 128;
  const int NC = in_sizes[1] / 64;
  const int NA = in_sizes[2] / 64;
  const int E  = in_sizes[3];
  const int SMAX = (NC > NA) ? NC : NA;

  // ---- workspace layout (float units) ----
  float* base = (float*)d_ws;
  size_t o = 0;
  ushort* A = (ushort*)(base + o); o += (size_t)NM * 64;   // movie features bf16
  ushort* xmh = (ushort*)(base + o); o += (size_t)NM * 64; // xm as bf16
  float* S = base + o; o += (size_t)SMAX * 128;            // S1h/S2h; ranks early
  ushort* S3h = (ushort*)(base + o); o += (size_t)SMAX * 64;  // xc/B transform out
  ushort* S4h = (ushort*)(base + o); o += (size_t)SMAX * 64;  // xa/C transform out
  ushort* B = (ushort*)(base + o); o += (size_t)NC * 64;   // xc1 pre-relu, bf16
  ushort* C = (ushort*)(base + o); o += (size_t)NA * 64;   // xa1 pre-relu, bf16
  int* cnt_m_cm = (int*)(base + o); o += NM;               // contiguous cnt block
  int* cnt_m_am = (int*)(base + o); o += NM;
  int* cnt_c    = (int*)(base + o); o += NC;
  int* cnt_a    = (int*)(base + o); o += NA;
  float* rinv_m_cm = base + o; o += NM;                    // rinv block (same order)
  float* rinv_m_am = base + o; o += NM;
  float* rinv_c    = base + o; o += NC;
  float* rinv_a    = base + o; o += NA;
  int* rp_m_cm = (int*)(base + o); o += NM + 1;
  int* rp_m_am = (int*)(base + o); o += NM + 1;
  int* rp_c    = (int*)(base + o); o += NC + 1;
  int* rp_a    = (int*)(base + o); o += NA + 1;
  int* pm_m_cm = (int*)(base + o); o += E;
  int* pm_m_am = (int*)(base + o); o += E;
  int* pm_c    = (int*)(base + o); o += E;
  int* pm_a    = (int*)(base + o); o += E;
  int* bsum    = (int*)(base + o); o += 4096;
  float* b0c  = base + o; o += 128;
  float* b1c  = base + o; o += 128;
  ushort* WT_r0   = (ushort*)(base + o); o += 8192;
  ushort* WT_r1   = (ushort*)(base + o); o += 8192;
  ushort* WT_mc0l = (ushort*)(base + o); o += 8192;
  ushort* WT_ma0l = (ushort*)(base + o); o += 8192;
  ushort* WT_cm1  = (ushort*)(base + o); o += 8192;
  ushort* WT_am1  = (ushort*)(base + o); o += 8192;
  ushort* WT_mc0r = (ushort*)(base + o); o += 4096;
  ushort* WT_ma0r = (ushort*)(base + o); o += 4096;
  ushort* WT_cm0  = (ushort*)(base + o); o += 4096;
  ushort* WT_am0  = (ushort*)(base + o); o += 4096;

  if (ws_size < o * sizeof(float)) return;  // diagnostic guard

  // ranks overlay S (S written only after fillr completes)
  int* rk_m_cm = (int*)S;
  int* rk_c    = rk_m_cm + E;
  int* rk_m_am = rk_m_cm + 2 * E;
  int* rk_a    = rk_m_cm + 3 * E;
  ushort* S1h = (ushort*)S;
  ushort* S2h = S1h + (size_t)SMAX * 128;

  float* outf = (float*)d_out;
  const int g2E = (2 * E + TPB - 1) / TPB;
  const int nbm = (NM + TPB - 1) / TPB;
  const int nbc = (NC + TPB - 1) / TPB;
  const int nba = (NA + TPB - 1) / TPB;
  const int nbtot = 2 * nbm + nbc + nba;
  const int nodes_total = 2 * NM + NC + NA;
  const ll n8 = (ll)NM * 16;
  const int gConv = (int)((n8 + TPB - 1) / TPB);

  PJobs J;
  J.a[0] = Wr_cm_0; J.bavg[0] = Wr_am_0; J.out[0] = WT_r0;
  J.a[1] = Wr_cm_1; J.bavg[1] = Wr_am_1; J.out[1] = WT_r1;
  J.a[2] = Wl_mc_0; J.bavg[2] = nullptr; J.out[2] = WT_mc0l;
  J.a[3] = Wl_ma_0; J.bavg[3] = nullptr; J.out[3] = WT_ma0l;
  J.a[4] = Wl_cm_1; J.bavg[4] = nullptr; J.out[4] = WT_cm1;
  J.a[5] = Wl_am_1; J.bavg[5] = nullptr; J.out[5] = WT_am1;
  J.a[6] = Wr_mc_0; J.bavg[6] = nullptr; J.out[6] = WT_mc0r;
  J.a[7] = Wr_ma_0; J.bavg[7] = nullptr; J.out[7] = WT_ma0r;
  J.a[8] = Wl_cm_0; J.bavg[8] = nullptr; J.out[8] = WT_cm0;
  J.a[9] = Wl_am_0; J.bavg[9] = nullptr; J.out[9] = WT_am0;
  J.ba[0] = b_cm_0; J.bb[0] = b_am_0; J.bo[0] = b0c;
  J.ba[1] = b_cm_1; J.bb[1] = b_am_1; J.bo[1] = b1c;

  // 1) mega1: NT convert || counts+ranks || weight prep
  hipMemsetAsync(cnt_m_cm, 0, sizeof(int) * (size_t)nodes_total, stream);
  mega1_k<<<gConv + g2E + 513, TPB, 0, stream>>>(
      xm, xmh, n8, gConv, src_cm, dst_cm, src_am, dst_am, E, g2E,
      cnt_m_cm, cnt_m_am, cnt_c, cnt_a, rk_m_cm, rk_c, rk_m_am, rk_a, J);

  // 2) blocksum || rinv, scan, finalize, atomic-free fill (standalone, full occupancy)
  {
    int gR = (nodes_total + TPB - 1) / TPB;
    bsum_rinv_k<<<nbtot + gR, TPB, 0, stream>>>(cnt_m_cm, NM, cnt_m_am, NM,
                                                cnt_c, NC, cnt_a, NA, bsum,
                                                rinv_m_cm, 2 * NM, nodes_total, nbtot);
  }
  scan_all_k<<<4, TPB, 0, stream>>>(bsum, NM, NM, NC, NA);
  finalize_all_k<<<nbtot, TPB, 0, stream>>>(cnt_m_cm, NM, rp_m_cm, cnt_m_am, NM, rp_m_am,
                                            cnt_c, NC, rp_c, cnt_a, NA, rp_a, bsum);
  fillr_k<<<g2E, TPB, 0, stream>>>(src_cm, dst_cm, src_am, dst_am, E,
                                   rp_m_cm, rp_m_am, rp_c, rp_a,
                                   rk_m_cm, rk_c, rk_m_am, rk_a,
                                   pm_m_cm, pm_m_am, pm_c, pm_a);

  const int gM = (NM + 127) / 128;
  const int gC = (NC + 127) / 128;
  const int gA = (NA + 127) / 128;
  const int gnM = (NM + 15) / 16;
  const int gwc = (NC + 15) / 16;
  const int gwa = (NA + 15) / 16;
  CArgs Z = {};

  // ---- layer 0: crew & cast movie-mean gathers (merged, bf16 source) ----
  gatherw2_k<<<gwc + gwa, TPB, 0, stream>>>(xmh, rp_c, pm_c, rinv_c, NC, S1h,
                                            rp_a, pm_a, rinv_a, NA, S2h, gwc);
  // L0 mega: crew/cast combines + movie Wr0 + xc/xa transforms (5 problems)
  {
    CArgs ac = {S1h, WT_mc0l, 128, 1, xc, WT_mc0r, 64, 0, 2, b_mc_0, B, NC, gC};
    CArgs aa = {S2h, WT_ma0l, 128, 1, xa, WT_ma0r, 64, 0, 2, b_ma_0, C, NA, gA};
    CArgs am = {xmh, WT_r0, 128, 1, nullptr, nullptr, 0, 0, 1, b0c, A, NM, gM};
    CArgs tc = {xc, WT_cm0, 64, 0, nullptr, nullptr, 0, 0, 1, nullptr, S3h, NC, gC};
    CArgs ta = {xa, WT_am0, 64, 0, nullptr, nullptr, 0, 0, 1, nullptr, S4h, NA, gA};
    mfma5_k<false><<<gC + gA + gM + gC + gA, TPB, 0, stream>>>(ac, aa, am, tc, ta);
  }
  gather2_k<<<gnM, TPB, 0, stream>>>(S3h, S4h, rp_m_cm, pm_m_cm, rinv_m_cm,
                                     rp_m_am, pm_m_am, rinv_m_am, NM, A);
  // A = xm1 pre-relu (bf16)

  // ---- layer 1: movie self-GEMM (in-place) + B/C transforms (3 problems) ----
  {
    CArgs am = {A, WT_r1, 128, 1, nullptr, nullptr, 0, 0, 1, b1c, A, NM, gM};
    CArgs ac = {B, WT_cm1, 128, 1, nullptr, nullptr, 0, 0, 1, nullptr, S3h, NC, gC};
    CArgs aa = {C, WT_am1, 128, 1, nullptr, nullptr, 0, 0, 1, nullptr, S4h, NA, gA};
    mfma5_k<true><<<gM + gC + gA, TPB, 0, stream>>>(am, ac, aa, Z, Z);
  }
  gather2_k<<<gnM, TPB, 0, stream>>>(S3h, S4h, rp_m_cm, pm_m_cm, rinv_m_cm,
                                     rp_m_am, pm_m_am, rinv_m_am, NM, A);
  // A = xm2 pre-relu (bf16)

  // ---- final linear ----
  final_k<<<(NM + TPB - 1) / TPB, TPB, 0, stream>>>(A, lin_W, lin_b, outf, NM);
}

// Round 15
// 555.036 us; speedup vs baseline: 1.0376x; 1.0097x over previous
//
#include <hip/hip_runtime.h>

#define TPB 256
typedef unsigned int uint;
typedef unsigned short ushort;
typedef long long ll;
typedef __attribute__((ext_vector_type(8))) short bf16x8;
typedef __attribute__((ext_vector_type(8))) ushort u16x8;
typedef __attribute__((ext_vector_type(4))) float f32x4;

__device__ __forceinline__ float bf2f(ushort h) {
  return __uint_as_float(((uint)h) << 16);
}
__device__ __forceinline__ ushort f2bf(float f) {
  uint u = __float_as_uint(f);
  u += 0x7fffu + ((u >> 16) & 1u);
  return (ushort)(u >> 16);
}

// ---------------- one-dispatch prep payload ----------------
struct PJobs {
  const float* a[10];
  const float* bavg[10];
  ushort* out[10];
  const float* ba[2];
  const float* bb[2];
  float* bo[2];
};

// ------- mega1: convert (BW, non-temporal) || rank (atomic-latency) || prep ---------
__global__ __launch_bounds__(TPB) void mega1_k(
    const float* __restrict__ xm, ushort* __restrict__ xmh, ll n8, int gConv,
    const int* __restrict__ src_cm, const int* __restrict__ dst_cm,
    const int* __restrict__ src_am, const int* __restrict__ dst_am, int E, int g2E,
    int* __restrict__ cnt_m_cm, int* __restrict__ cnt_m_am,
    int* __restrict__ cnt_c, int* __restrict__ cnt_a,
    int* __restrict__ rk_m_cm, int* __restrict__ rk_c,
    int* __restrict__ rk_m_am, int* __restrict__ rk_a,
    PJobs J) {
  int b = blockIdx.x;
  int t = threadIdx.x;
  if (b < gConv) {  // xm f32 -> bf16 (non-temporal: bypass L2, protect cnt residency)
    ll i = (ll)b * TPB + t;
    if (i >= n8) return;
    const f32x4* p = (const f32x4*)(xm + i * 8);
    f32x4 a = __builtin_nontemporal_load(p);
    f32x4 bb = __builtin_nontemporal_load(p + 1);
    u16x8 v;
    v[0] = f2bf(a[0]); v[1] = f2bf(a[1]); v[2] = f2bf(a[2]); v[3] = f2bf(a[3]);
    v[4] = f2bf(bb[0]); v[5] = f2bf(bb[1]); v[6] = f2bf(bb[2]); v[7] = f2bf(bb[3]);
    __builtin_nontemporal_store(v, (u16x8*)&xmh[i * 8]);
    return;
  }
  b -= gConv;
  if (b < g2E) {  // counts + per-edge local rank (one atomic pass)
    int i = b * TPB + t;
    if (i < E) {
      rk_m_cm[i] = atomicAdd(&cnt_m_cm[dst_cm[i]], 1);
      rk_c[i]    = atomicAdd(&cnt_c[src_cm[i]], 1);
    } else if (i < 2 * E) {
      int e = i - E;
      rk_m_am[e] = atomicAdd(&cnt_m_am[dst_am[e]], 1);
      rk_a[e]    = atomicAdd(&cnt_a[src_am[e]], 1);
    }
    return;
  }
  b -= g2E;  // prep: 10 weight transposes + 2 bias averages (513 blocks)
  if (b == 512) {
    if (t < 128) J.bo[0][t] = 0.5f * (J.ba[0][t] + J.bb[0][t]);
    else if (t < 256) J.bo[1][t - 128] = 0.5f * (J.ba[1][t - 128] + J.bb[1][t - 128]);
    return;
  }
  int job, idx, K;
  if (b < 384) { job = b >> 6; idx = ((b & 63) << 8) | t; K = 128; }
  else { int bb2 = b - 384; job = 6 + (bb2 >> 5); idx = ((bb2 & 31) << 8) | t; K = 64; }
  int col = idx / K, k = idx - col * K;
  float v = J.a[job][k * 128 + col];
  if (J.bavg[job]) v = 0.5f * (v + J.bavg[job][k * 128 + col]);
  J.out[job][idx] = f2bf(v);
}

// ---------------- CSR build helpers ----------------
__device__ __forceinline__ void rel_map(int b, int nb0, int nb1, int nb2, int nb3,
                                        int& r, int& lb) {
  if (b < nb0) { r = 0; lb = b; }
  else if (b < nb0 + nb1) { r = 1; lb = b - nb0; }
  else if (b < nb0 + nb1 + nb2) { r = 2; lb = b - nb0 - nb1; }
  else { r = 3; lb = b - nb0 - nb1 - nb2; }
}

__global__ __launch_bounds__(TPB) void bsum_rinv_k(
    const int* __restrict__ c0, int n0, const int* __restrict__ c1, int n1,
    const int* __restrict__ c2, int n2, const int* __restrict__ c3, int n3,
    int* __restrict__ bsum, float* __restrict__ rinv, int nm2, int total, int nbtot) {
  __shared__ int lds[TPB];
  int b = blockIdx.x;
  int t = threadIdx.x;
  if (b >= nbtot) {  // rinv branch (cnt block contiguous at c0)
    int i = (b - nbtot) * TPB + t;
    if (i < total) {
      float scale = (i < nm2) ? 0.5f : 1.0f;
      rinv[i] = scale / fmaxf((float)c0[i], 1.0f);
    }
    return;
  }
  int nb0 = (n0 + TPB - 1) / TPB, nb1 = (n1 + TPB - 1) / TPB;
  int nb2 = (n2 + TPB - 1) / TPB, nb3 = (n3 + TPB - 1) / TPB;
  int r, lb;
  rel_map(b, nb0, nb1, nb2, nb3, r, lb);
  const int* cnt = (r == 0) ? c0 : (r == 1) ? c1 : (r == 2) ? c2 : c3;
  int n = (r == 0) ? n0 : (r == 1) ? n1 : (r == 2) ? n2 : n3;
  int i = lb * TPB + t;
  lds[t] = (i < n) ? cnt[i] : 0;
  __syncthreads();
  for (int off = 128; off > 0; off >>= 1) {
    if (t < off) lds[t] += lds[t + off];
    __syncthreads();
  }
  if (t == 0) bsum[r * 1024 + lb] = lds[0];
}

__global__ __launch_bounds__(TPB) void scan_all_k(int* __restrict__ bsum,
                                                  int n0, int n1, int n2, int n3) {
  __shared__ int lds[TPB];
  int r = blockIdx.x;
  int n = (r == 0) ? n0 : (r == 1) ? n1 : (r == 2) ? n2 : n3;
  int nb = (n + TPB - 1) / TPB;
  int* bs = bsum + r * 1024;
  int t = threadIdx.x;
  int offset = 0;
  for (int base = 0; base < nb; base += TPB) {
    int v = (base + t < nb) ? bs[base + t] : 0;
    lds[t] = v;
    __syncthreads();
    for (int off = 1; off < TPB; off <<= 1) {
      int add = (t >= off) ? lds[t - off] : 0;
      __syncthreads();
      lds[t] += add;
      __syncthreads();
    }
    int incl = lds[t];
    if (base + t < nb) bs[base + t] = offset + incl - v;
    int tot = lds[TPB - 1];
    __syncthreads();
    offset += tot;
  }
}

__global__ __launch_bounds__(TPB) void finalize_all_k(
    const int* __restrict__ c0, int n0, int* __restrict__ rp0,
    const int* __restrict__ c1, int n1, int* __restrict__ rp1,
    const int* __restrict__ c2, int n2, int* __restrict__ rp2,
    const int* __restrict__ c3, int n3, int* __restrict__ rp3,
    const int* __restrict__ bsum) {
  __shared__ int lds[TPB];
  int nb0 = (n0 + TPB - 1) / TPB, nb1 = (n1 + TPB - 1) / TPB;
  int nb2 = (n2 + TPB - 1) / TPB, nb3 = (n3 + TPB - 1) / TPB;
  int r, lb;
  rel_map(blockIdx.x, nb0, nb1, nb2, nb3, r, lb);
  const int* cnt = (r == 0) ? c0 : (r == 1) ? c1 : (r == 2) ? c2 : c3;
  int* rowptr = (r == 0) ? rp0 : (r == 1) ? rp1 : (r == 2) ? rp2 : rp3;
  int n = (r == 0) ? n0 : (r == 1) ? n1 : (r == 2) ? n2 : n3;
  int t = threadIdx.x;
  int i = lb * TPB + t;
  int v = (i < n) ? cnt[i] : 0;
  lds[t] = v;
  __syncthreads();
  for (int off = 1; off < TPB; off <<= 1) {
    int add = (t >= off) ? lds[t - off] : 0;
    __syncthreads();
    lds[t] += add;
    __syncthreads();
  }
  int ex = lds[t] - v + bsum[r * 1024 + lb];
  if (i < n) {
    rowptr[i] = ex;
    if (i == n - 1) rowptr[n] = ex + v;
  }
}

// fill crew/cast perms only (1 store per thread; movie perms deferred)
__global__ __launch_bounds__(TPB) void fillca_k(const int* __restrict__ src_cm,
                                                const int* __restrict__ dst_cm,
                                                const int* __restrict__ src_am,
                                                const int* __restrict__ dst_am, int E,
                                                const int* __restrict__ rp_c,
                                                const int* __restrict__ rp_a,
                                                const int* __restrict__ rk_c,
                                                const int* __restrict__ rk_a,
                                                int* __restrict__ pm_c,
                                                int* __restrict__ pm_a) {
  int i = blockIdx.x * blockDim.x + threadIdx.x;
  if (i < E) {
    pm_c[rp_c[src_cm[i]] + rk_c[i]] = dst_cm[i];
  } else if (i < 2 * E) {
    int e = i - E;
    pm_a[rp_a[src_am[e]] + rk_a[e]] = dst_am[e];
  }
}

// ---- gwfill: movie-perm fill (latency/scatter) || crew+cast gathers (latency) ------
// Both sections LDS-free & latency-bound -> co-scheduling hides the fill.
__global__ __launch_bounds__(TPB) void gwfill_k(
    const int* __restrict__ src_cm, const int* __restrict__ dst_cm,
    const int* __restrict__ src_am, const int* __restrict__ dst_am, int E, int gFill,
    const int* __restrict__ rp_m_cm, const int* __restrict__ rp_m_am,
    const int* __restrict__ rk_m_cm, const int* __restrict__ rk_m_am,
    int* __restrict__ pm_m_cm, int* __restrict__ pm_m_am,
    const ushort* __restrict__ xmh,
    const int* __restrict__ rp1, const int* __restrict__ pm1,
    const float* __restrict__ ri1, int N1, ushort* __restrict__ o1,
    const int* __restrict__ rp2, const int* __restrict__ pm2,
    const float* __restrict__ ri2, int N2, ushort* __restrict__ o2, int g1) {
  int b = blockIdx.x;
  if (b < gFill) {  // movie-perm fill (consumed 3 dispatches later by gather2)
    int i = b * TPB + threadIdx.x;
    if (i < E) {
      pm_m_cm[rp_m_cm[dst_cm[i]] + rk_m_cm[i]] = src_cm[i];
    } else if (i < 2 * E) {
      int e = i - E;
      pm_m_am[rp_m_am[dst_am[e]] + rk_m_am[e]] = src_am[e];
    }
    return;
  }
  b -= gFill;
  const int* rowptr; const int* perm; const float* rinv; int N; ushort* out;
  int lb;
  if (b < g1) { rowptr = rp1; perm = pm1; rinv = ri1; N = N1; out = o1; lb = b; }
  else { rowptr = rp2; perm = pm2; rinv = ri2; N = N2; out = o2; lb = b - g1; }
  int nid = lb * 16 + (threadIdx.x >> 4);
  if (nid >= N) return;
  int d = (threadIdx.x & 15) << 3;
  int j = rowptr[nid], e = rowptr[nid + 1];
  float aA[8] = {0.f}, aB[8] = {0.f};
  for (; j + 1 < e; j += 2) {
    u16x8 v0 = *(const u16x8*)&xmh[((ll)perm[j] << 7) + d];
    u16x8 v1 = *(const u16x8*)&xmh[((ll)perm[j + 1] << 7) + d];
#pragma unroll
    for (int k = 0; k < 8; ++k) { aA[k] += bf2f(v0[k]); aB[k] += bf2f(v1[k]); }
  }
  if (j < e) {
    u16x8 v0 = *(const u16x8*)&xmh[((ll)perm[j] << 7) + d];
#pragma unroll
    for (int k = 0; k < 8; ++k) aA[k] += bf2f(v0[k]);
  }
  float r = rinv[nid];
  u16x8 o;
#pragma unroll
  for (int k = 0; k < 8; ++k) o[k] = f2bf((aA[k] + aB[k]) * r);
  *(u16x8*)&out[((ll)nid << 7) + d] = o;
}

// -------- dual-CSR gather into bf16 A (single RMW), 2-way unrolled ------------------
__global__ __launch_bounds__(TPB) void gather2_k(
    const ushort* __restrict__ s1, const ushort* __restrict__ s2,
    const int* __restrict__ rp1, const int* __restrict__ pm1, const float* __restrict__ ri1,
    const int* __restrict__ rp2, const int* __restrict__ pm2, const float* __restrict__ ri2,
    int N, ushort* __restrict__ out) {
  int nid = blockIdx.x * 16 + (threadIdx.x >> 4);
  if (nid >= N) return;
  int d = (threadIdx.x & 15) << 3;
  float aA[8] = {0.f}, aB[8] = {0.f};
  {
    int j = rp1[nid], e = rp1[nid + 1];
    for (; j + 1 < e; j += 2) {
      u16x8 v0 = *(const u16x8*)&s1[((ll)pm1[j] << 7) + d];
      u16x8 v1 = *(const u16x8*)&s1[((ll)pm1[j + 1] << 7) + d];
#pragma unroll
      for (int k = 0; k < 8; ++k) { aA[k] += bf2f(v0[k]); aB[k] += bf2f(v1[k]); }
    }
    if (j < e) {
      u16x8 v0 = *(const u16x8*)&s1[((ll)pm1[j] << 7) + d];
#pragma unroll
      for (int k = 0; k < 8; ++k) aA[k] += bf2f(v0[k]);
    }
  }
  float r1 = ri1[nid];
  float res[8];
#pragma unroll
  for (int k = 0; k < 8; ++k) res[k] = (aA[k] + aB[k]) * r1;
  float bA[8] = {0.f}, bB[8] = {0.f};
  {
    int j = rp2[nid], e = rp2[nid + 1];
    for (; j + 1 < e; j += 2) {
      u16x8 v0 = *(const u16x8*)&s2[((ll)pm2[j] << 7) + d];
      u16x8 v1 = *(const u16x8*)&s2[((ll)pm2[j + 1] << 7) + d];
#pragma unroll
      for (int k = 0; k < 8; ++k) { bA[k] += bf2f(v0[k]); bB[k] += bf2f(v1[k]); }
    }
    if (j < e) {
      u16x8 v0 = *(const u16x8*)&s2[((ll)pm2[j] << 7) + d];
#pragma unroll
      for (int k = 0; k < 8; ++k) bA[k] += bf2f(v0[k]);
    }
  }
  float r2 = ri2[nid];
  ushort* p = &out[((ll)nid << 7) + d];
  u16x8 cur = *(u16x8*)p;
  u16x8 o;
#pragma unroll
  for (int k = 0; k < 8; ++k)
    o[k] = f2bf(bf2f(cur[k]) + res[k] + (bA[k] + bB[k]) * r2);
  *(u16x8*)p = o;
}

// ---------------- final linear: relu(X bf16) (M x 128) @ (128 x 16) + b -------------
__global__ __launch_bounds__(TPB) void final_k(const ushort* __restrict__ X,
                                               const float* __restrict__ W,
                                               const float* __restrict__ b,
                                               float* __restrict__ out, int M) {
  __shared__ float lw[128 * 16];
  __shared__ float lb[16];
  int t = threadIdx.x;
  for (int i = t; i < 2048; i += TPB) lw[i] = W[i];
  if (t < 16) lb[t] = b[t];
  __syncthreads();
  ll row = (ll)blockIdx.x * TPB + t;
  if (row >= M) return;
  float acc[16];
#pragma unroll
  for (int c = 0; c < 16; ++c) acc[c] = lb[c];
  const ushort* xr = &X[row * 128];
  for (int k = 0; k < 128; k += 8) {
    u16x8 xv = *(const u16x8*)&xr[k];
#pragma unroll
    for (int j = 0; j < 8; ++j) {
      float xs = fmaxf(bf2f(xv[j]), 0.f);
#pragma unroll
      for (int c = 0; c < 16; ++c) acc[c] = fmaf(xs, lw[(k + j) * 16 + c], acc[c]);
    }
  }
#pragma unroll
  for (int c = 0; c < 16; c += 4) {
    float4 o; o.x = acc[c]; o.y = acc[c + 1]; o.z = acc[c + 2]; o.w = acc[c + 3];
    *(float4*)&out[row * 16 + c] = o;
  }
}

// ---------------- MFMA multi-segment GEMM (+bias), N=128, 5-problem -----------------
#define BK 64
#define XPITCH 72
#define CPITCH 132
struct CArgs {
  const void* X0; const ushort* WT0; int K0; int xb0;
  const void* X1; const ushort* WT1; int K1; int xb1;
  int nseg; const float* bias; void* out; int M; int nblk;
};

template <bool XRELU>
__global__ __launch_bounds__(TPB) void mfma5_k(CArgs a0, CArgs a1, CArgs a2,
                                               CArgs a3, CArgs a4) {
  const int bx = blockIdx.x;
  const int o0 = a0.nblk, o1 = o0 + a1.nblk, o2 = o1 + a2.nblk, o3 = o2 + a3.nblk;
  const CArgs& a = (bx < o0) ? a0 : (bx < o1) ? a1 : (bx < o2) ? a2
                   : (bx < o3) ? a3 : a4;
  const int blk = bx - ((bx < o0) ? 0 : (bx < o1) ? o0 : (bx < o2) ? o1
                        : (bx < o3) ? o2 : o3);

  __shared__ ushort sbuf[2 * 128 * XPITCH];
  ushort* Xs = sbuf;
  ushort* Ws = sbuf + 128 * XPITCH;
  const int t = threadIdx.x;
  const int lane = t & 63;
  const int wid = t >> 6;
  const int wm = (wid >> 1) << 6;
  const int wn = (wid & 1) << 6;
  const ll rbase = (ll)blk * 128;
  const int M = a.M;

  f32x4 acc[4][4];
#pragma unroll
  for (int mi = 0; mi < 4; ++mi)
#pragma unroll
    for (int ni = 0; ni < 4; ++ni) acc[mi][ni] = (f32x4){0.f, 0.f, 0.f, 0.f};

  for (int s = 0; s < a.nseg; ++s) {
    const void* Xv = s ? a.X1 : a.X0;
    const ushort* WT = s ? a.WT1 : a.WT0;
    const int K = s ? a.K1 : a.K0;
    const int xb = s ? a.xb1 : a.xb0;
    for (int k0 = 0; k0 < K; k0 += BK) {
      __syncthreads();
#pragma unroll
      for (int i = 0; i < 4; ++i) {
        int idx8 = t + i * TPB;
        int row = idx8 >> 3;
        int kb = (idx8 & 7) << 3;
        u16x8 xv;
        ll grow = rbase + row;
        if (grow < M) {
          if (xb) {
            xv = *(const u16x8*)((const ushort*)Xv + grow * K + k0 + kb);
            if (XRELU) {
#pragma unroll
              for (int j = 0; j < 8; ++j) xv[j] = (xv[j] & 0x8000u) ? (ushort)0 : xv[j];
            }
          } else {
            const float* xp = (const float*)Xv + grow * K + k0 + kb;
            float4 va = *(const float4*)xp;
            float4 vb = *(const float4*)(xp + 4);
            if (XRELU) {
              va.x = fmaxf(va.x, 0.f); va.y = fmaxf(va.y, 0.f);
              va.z = fmaxf(va.z, 0.f); va.w = fmaxf(va.w, 0.f);
              vb.x = fmaxf(vb.x, 0.f); vb.y = fmaxf(vb.y, 0.f);
              vb.z = fmaxf(vb.z, 0.f); vb.w = fmaxf(vb.w, 0.f);
            }
            xv[0] = f2bf(va.x); xv[1] = f2bf(va.y); xv[2] = f2bf(va.z); xv[3] = f2bf(va.w);
            xv[4] = f2bf(vb.x); xv[5] = f2bf(vb.y); xv[6] = f2bf(vb.z); xv[7] = f2bf(vb.w);
          }
        } else {
#pragma unroll
          for (int j = 0; j < 8; ++j) xv[j] = 0;
        }
        *(u16x8*)&Xs[row * XPITCH + kb] = xv;
        *(u16x8*)&Ws[row * XPITCH + kb] = *(const u16x8*)(WT + (ll)row * K + k0 + kb);
      }
      __syncthreads();
#pragma unroll
      for (int kk = 0; kk < BK; kk += 32) {
        const int krow = kk + ((lane >> 4) << 3);
        bf16x8 af[4], bfr[4];
#pragma unroll
        for (int mi = 0; mi < 4; ++mi)
          af[mi] = *(const bf16x8*)&Xs[(wm + mi * 16 + (lane & 15)) * XPITCH + krow];
#pragma unroll
        for (int ni = 0; ni < 4; ++ni)
          bfr[ni] = *(const bf16x8*)&Ws[(wn + ni * 16 + (lane & 15)) * XPITCH + krow];
#pragma unroll
        for (int mi = 0; mi < 4; ++mi)
#pragma unroll
          for (int ni = 0; ni < 4; ++ni)
            acc[mi][ni] = __builtin_amdgcn_mfma_f32_16x16x32_bf16(af[mi], bfr[ni],
                                                                  acc[mi][ni], 0, 0, 0);
      }
    }
  }

  __syncthreads();

  {
    const int colb = wn + (lane & 15);
    const int rsub = (lane >> 4) << 2;
#pragma unroll
    for (int ni = 0; ni < 4; ++ni) {
      int col = colb + ni * 16;
      float bv = a.bias ? a.bias[col] : 0.f;
#pragma unroll
      for (int mi = 0; mi < 4; ++mi) {
        int row0 = wm + mi * 16 + rsub;
#pragma unroll
        for (int j = 0; j < 4; ++j)
          sbuf[(row0 + j) * CPITCH + col] = f2bf(acc[mi][ni][j] + bv);
      }
    }
  }
  __syncthreads();
  {
    int lrow = t >> 1;
    int half = t & 1;
    ll grow = rbase + lrow;
    if (grow < M) {
      const ushort* src = &sbuf[lrow * CPITCH + half * 64];
      ushort* dst = (ushort*)a.out + grow * 128 + half * 64;
#pragma unroll
      for (int k = 0; k < 8; ++k)
        *(u16x8*)(dst + k * 8) = *(const u16x8*)(src + k * 8);
    }
  }
}

// ---------------- launch ----------------
extern "C" void kernel_launch(void* const* d_in, const int* in_sizes, int n_in,
                              void* d_out, int out_size, void* d_ws, size_t ws_size,
                              hipStream_t stream) {
  const float* xm = (const float*)d_in[0];
  const float* xc = (const float*)d_in[1];
  const float* xa = (const float*)d_in[2];
  const int* src_cm = (const int*)d_in[3];
  const int* dst_cm = (const int*)d_in[4];
  const int* src_am = (const int*)d_in[5];
  const int* dst_am = (const int*)d_in[6];
  const float* Wl_cm_0 = (const float*)d_in[7];
  const float* Wr_cm_0 = (const float*)d_in[8];
  const float* b_cm_0  = (const float*)d_in[9];
  const float* Wl_am_0 = (const float*)d_in[10];
  const float* Wr_am_0 = (const float*)d_in[11];
  const float* b_am_0  = (const float*)d_in[12];
  const float* Wl_mc_0 = (const float*)d_in[13];
  const float* Wr_mc_0 = (const float*)d_in[14];
  const float* b_mc_0  = (const float*)d_in[15];
  const float* Wl_ma_0 = (const float*)d_in[16];
  const float* Wr_ma_0 = (const float*)d_in[17];
  const float* b_ma_0  = (const float*)d_in[18];
  const float* Wl_cm_1 = (const float*)d_in[19];
  const float* Wr_cm_1 = (const float*)d_in[20];
  const float* b_cm_1  = (const float*)d_in[21];
  const float* Wl_am_1 = (const float*)d_in[22];
  const float* Wr_am_1 = (const float*)d_in[23];
  const float* b_am_1  = (const float*)d_in[24];
  const float* lin_W   = (const float*)d_in[31];
  const float* lin_b   = (const float*)d_in[32];

  const int NM = in_sizes[0] / 128;
  const int NC = in_sizes[1] / 64;
  const int NA = in_sizes[2] / 64;
  const int E  = in_sizes[3];
  const int SMAX = (NC > NA) ? NC : NA;

  // ---- workspace layout (float units) ----
  float* base = (float*)d_ws;
  size_t o = 0;
  ushort* A = (ushort*)(base + o); o += (size_t)NM * 64;   // movie features bf16
  ushort* xmh = (ushort*)(base + o); o += (size_t)NM * 64; // xm as bf16
  float* S = base + o; o += (size_t)SMAX * 128;            // S1h/S2h bf16 halves
  ushort* S3h = (ushort*)(base + o); o += (size_t)SMAX * 64;
  ushort* S4h = (ushort*)(base + o); o += (size_t)SMAX * 64;
  ushort* B = (ushort*)(base + o); o += (size_t)NC * 64;
  ushort* C = (ushort*)(base + o); o += (size_t)NA * 64;
  int* cnt_m_cm = (int*)(base + o); o += NM;               // contiguous cnt block
  int* cnt_m_am = (int*)(base + o); o += NM;
  int* cnt_c    = (int*)(base + o); o += NC;
  int* cnt_a    = (int*)(base + o); o += NA;
  float* rinv_m_cm = base + o; o += NM;                    // rinv block (same order)
  float* rinv_m_am = base + o; o += NM;
  float* rinv_c    = base + o; o += NC;
  float* rinv_a    = base + o; o += NA;
  int* rp_m_cm = (int*)(base + o); o += NM + 1;
  int* rp_m_am = (int*)(base + o); o += NM + 1;
  int* rp_c    = (int*)(base + o); o += NC + 1;
  int* rp_a    = (int*)(base + o); o += NA + 1;
  int* pm_m_cm = (int*)(base + o); o += E;
  int* pm_m_am = (int*)(base + o); o += E;
  int* pm_c    = (int*)(base + o); o += E;
  int* pm_a    = (int*)(base + o); o += E;
  int* rk_m_cm = (int*)(base + o); o += E;                 // dedicated rank arrays
  int* rk_c    = (int*)(base + o); o += E;                 // (no S overlay: gwfill
  int* rk_m_am = (int*)(base + o); o += E;                 //  writes S1h while reading
  int* rk_a    = (int*)(base + o); o += E;                 //  movie ranks)
  int* bsum    = (int*)(base + o); o += 4096;
  float* b0c  = base + o; o += 128;
  float* b1c  = base + o; o += 128;
  ushort* WT_r0   = (ushort*)(base + o); o += 8192;
  ushort* WT_r1   = (ushort*)(base + o); o += 8192;
  ushort* WT_mc0l = (ushort*)(base + o); o += 8192;
  ushort* WT_ma0l = (ushort*)(base + o); o += 8192;
  ushort* WT_cm1  = (ushort*)(base + o); o += 8192;
  ushort* WT_am1  = (ushort*)(base + o); o += 8192;
  ushort* WT_mc0r = (ushort*)(base + o); o += 4096;
  ushort* WT_ma0r = (ushort*)(base + o); o += 4096;
  ushort* WT_cm0  = (ushort*)(base + o); o += 4096;
  ushort* WT_am0  = (ushort*)(base + o); o += 4096;

  if (ws_size < o * sizeof(float)) return;  // diagnostic guard

  ushort* S1h = (ushort*)S;
  ushort* S2h = S1h + (size_t)SMAX * 128;

  float* outf = (float*)d_out;
  const int g2E = (2 * E + TPB - 1) / TPB;
  const int nbm = (NM + TPB - 1) / TPB;
  const int nbc = (NC + TPB - 1) / TPB;
  const int nba = (NA + TPB - 1) / TPB;
  const int nbtot = 2 * nbm + nbc + nba;
  const int nodes_total = 2 * NM + NC + NA;
  const ll n8 = (ll)NM * 16;
  const int gConv = (int)((n8 + TPB - 1) / TPB);

  PJobs J;
  J.a[0] = Wr_cm_0; J.bavg[0] = Wr_am_0; J.out[0] = WT_r0;
  J.a[1] = Wr_cm_1; J.bavg[1] = Wr_am_1; J.out[1] = WT_r1;
  J.a[2] = Wl_mc_0; J.bavg[2] = nullptr; J.out[2] = WT_mc0l;
  J.a[3] = Wl_ma_0; J.bavg[3] = nullptr; J.out[3] = WT_ma0l;
  J.a[4] = Wl_cm_1; J.bavg[4] = nullptr; J.out[4] = WT_cm1;
  J.a[5] = Wl_am_1; J.bavg[5] = nullptr; J.out[5] = WT_am1;
  J.a[6] = Wr_mc_0; J.bavg[6] = nullptr; J.out[6] = WT_mc0r;
  J.a[7] = Wr_ma_0; J.bavg[7] = nullptr; J.out[7] = WT_ma0r;
  J.a[8] = Wl_cm_0; J.bavg[8] = nullptr; J.out[8] = WT_cm0;
  J.a[9] = Wl_am_0; J.bavg[9] = nullptr; J.out[9] = WT_am0;
  J.ba[0] = b_cm_0; J.bb[0] = b_am_0; J.bo[0] = b0c;
  J.ba[1] = b_cm_1; J.bb[1] = b_am_1; J.bo[1] = b1c;

  // 1) mega1: NT convert || counts+ranks || weight prep
  hipMemsetAsync(cnt_m_cm, 0, sizeof(int) * (size_t)nodes_total, stream);
  mega1_k<<<gConv + g2E + 513, TPB, 0, stream>>>(
      xm, xmh, n8, gConv, src_cm, dst_cm, src_am, dst_am, E, g2E,
      cnt_m_cm, cnt_m_am, cnt_c, cnt_a, rk_m_cm, rk_c, rk_m_am, rk_a, J);

  // 2) blocksum || rinv, scan, finalize
  {
    int gR = (nodes_total + TPB - 1) / TPB;
    bsum_rinv_k<<<nbtot + gR, TPB, 0, stream>>>(cnt_m_cm, NM, cnt_m_am, NM,
                                                cnt_c, NC, cnt_a, NA, bsum,
                                                rinv_m_cm, 2 * NM, nodes_total, nbtot);
  }
  scan_all_k<<<4, TPB, 0, stream>>>(bsum, NM, NM, NC, NA);
  finalize_all_k<<<nbtot, TPB, 0, stream>>>(cnt_m_cm, NM, rp_m_cm, cnt_m_am, NM, rp_m_am,
                                            cnt_c, NC, rp_c, cnt_a, NA, rp_a, bsum);

  // 3) crew/cast perm fill only (movie perms deferred into gwfill)
  fillca_k<<<g2E, TPB, 0, stream>>>(src_cm, dst_cm, src_am, dst_am, E,
                                    rp_c, rp_a, rk_c, rk_a, pm_c, pm_a);

  const int gM = (NM + 127) / 128;
  const int gC = (NC + 127) / 128;
  const int gA = (NA + 127) / 128;
  const int gnM = (NM + 15) / 16;
  const int gwc = (NC + 15) / 16;
  const int gwa = (NA + 15) / 16;
  CArgs Z = {};

  // 4) gwfill: movie-perm fill || crew & cast movie-mean gathers
  gwfill_k<<<g2E + gwc + gwa, TPB, 0, stream>>>(
      src_cm, dst_cm, src_am, dst_am, E, g2E,
      rp_m_cm, rp_m_am, rk_m_cm, rk_m_am, pm_m_cm, pm_m_am,
      xmh, rp_c, pm_c, rinv_c, NC, S1h, rp_a, pm_a, rinv_a, NA, S2h, gwc);

  // 5) L0 mega: crew/cast combines + movie Wr0 + xc/xa transforms (5 problems)
  {
    CArgs ac = {S1h, WT_mc0l, 128, 1, xc, WT_mc0r, 64, 0, 2, b_mc_0, B, NC, gC};
    CArgs aa = {S2h, WT_ma0l, 128, 1, xa, WT_ma0r, 64, 0, 2, b_ma_0, C, NA, gA};
    CArgs am = {xmh, WT_r0, 128, 1, nullptr, nullptr, 0, 0, 1, b0c, A, NM, gM};
    CArgs tc = {xc, WT_cm0, 64, 0, nullptr, nullptr, 0, 0, 1, nullptr, S3h, NC, gC};
    CArgs ta = {xa, WT_am0, 64, 0, nullptr, nullptr, 0, 0, 1, nullptr, S4h, NA, gA};
    mfma5_k<false><<<gC + gA + gM + gC + gA, TPB, 0, stream>>>(ac, aa, am, tc, ta);
  }
  gather2_k<<<gnM, TPB, 0, stream>>>(S3h, S4h, rp_m_cm, pm_m_cm, rinv_m_cm,
                                     rp_m_am, pm_m_am, rinv_m_am, NM, A);
  // A = xm1 pre-relu (bf16)

  // 6) layer 1: movie self-GEMM (in-place) + B/C transforms
  {
    CArgs am = {A, WT_r1, 128, 1, nullptr, nullptr, 0, 0, 1, b1c, A, NM, gM};
    CArgs ac = {B, WT_cm1, 128, 1, nullptr, nullptr, 0, 0, 1, nullptr, S3h, NC, gC};
    CArgs aa = {C, WT_am1, 128, 1, nullptr, nullptr, 0, 0, 1, nullptr, S4h, NA, gA};
    mfma5_k<true><<<gM + gC + gA, TPB, 0, stream>>>(am, ac, aa, Z, Z);
  }
  gather2_k<<<gnM, TPB, 0, stream>>>(S3h, S4h, rp_m_cm, pm_m_cm, rinv_m_cm,
                                     rp_m_am, pm_m_am, rinv_m_am, NM, A);
  // A = xm2 pre-relu (bf16)

  // ---- final linear ----
  final_k<<<(NM + TPB - 1) / TPB, TPB, 0, stream>>>(A, lin_W, lin_b, outf, NM);
}